// Round 13
// baseline (601.412 us; speedup 1.0000x reference)
//
#include <hip/hip_runtime.h>
#include <cstdint>
#include <cstddef>
#include <math.h>

#define SEQ   2048
#define DIM   2048
#define NQKV  6144
#define NH    16
#define DH    128
#define ROWS  4096   /* b*n */

typedef unsigned short u16;
typedef unsigned int u32;
typedef __attribute__((ext_vector_type(8))) short bf16x8;
typedef __attribute__((ext_vector_type(4))) float f32x4;

__device__ __forceinline__ u16 f2bf(float f) {
  union { float f; u32 u; } v;
  v.f = f;
  u32 r = v.u + 0x7FFFu + ((v.u >> 16) & 1u);
  return (u16)(r >> 16);
}

// ------------------------------------------------ rmsnorm (fp64, 1 wave/row)
// [VERIFIED round 4 — do not touch]
__global__ __launch_bounds__(64) void rms_slow(
    const float* __restrict__ x, const float* __restrict__ g,
    float* __restrict__ xn) {
  int row = blockIdx.x, lane = threadIdx.x;
  const float* xr = x + (size_t)row * DIM;
  double ss = 0.0;
  for (int c = lane; c < DIM; c += 64) { double v = xr[c]; ss += v * v; }
  #pragma unroll
  for (int off = 32; off >= 1; off >>= 1) ss += __shfl_xor(ss, off);
  double nrm = sqrt(ss); if (nrm < 1e-12) nrm = 1e-12;
  double sc = 45.254833995939045 / nrm;   // sqrt(2048)/||x||
  float* dst = xn + (size_t)row * DIM;
  for (int c = lane; c < DIM; c += 64) dst[c] = (float)((double)xr[c] * sc * (double)g[c]);
}

// ----------------------------------------- fp32 -> bf16 cast (8 elems/thread)
// [VERIFIED round 12 — unchanged]
__global__ __launch_bounds__(256) void cast_bf16(
    const float* __restrict__ in, u16* __restrict__ out) {
  size_t i = ((size_t)blockIdx.x * 256 + threadIdx.x) * 8;
  float4 f0 = *(const float4*)(in + i);
  float4 f1 = *(const float4*)(in + i + 4);
  union { u16 h[8]; int4 q; } cv;
  cv.h[0]=f2bf(f0.x); cv.h[1]=f2bf(f0.y); cv.h[2]=f2bf(f0.z); cv.h[3]=f2bf(f0.w);
  cv.h[4]=f2bf(f1.x); cv.h[5]=f2bf(f1.y); cv.h[6]=f2bf(f1.z); cv.h[7]=f2bf(f1.w);
  *(int4*)(out + i) = cv.q;
}

// ------------------------------------------------- fp32 -> bf16 transpose ---
// [VERIFIED round 12 — unchanged]
__global__ void transpose_f32_bf16(const float* __restrict__ in,
                                   u16* __restrict__ out, int R, int C) {
  __shared__ float tile[32][33];
  int bx = blockIdx.x * 32;   // C index
  int by = blockIdx.y * 32;   // R index
  int tx = threadIdx.x, ty = threadIdx.y;   // (32,8)
  #pragma unroll
  for (int j = 0; j < 32; j += 8)
    tile[ty + j][tx] = in[(size_t)(by + ty + j) * C + bx + tx];
  __syncthreads();
  #pragma unroll
  for (int j = 0; j < 32; j += 8)
    out[(size_t)(bx + ty + j) * R + by + tx] = f2bf(tile[tx][ty + j]);
}

// ------------------------------------------ bf16 NT GEMM, XCD-swizzled ------
// [VERIFIED round 12 — unchanged]
__global__ __launch_bounds__(256) void gemm_nt(
    const u16* __restrict__ A, const u16* __restrict__ BT,
    float* __restrict__ C, int M, int N, int K) {
  __shared__ u16 As[128 * 40];
  __shared__ u16 Bs[128 * 40];
  int nbn = N >> 7;
  int chunk = nbn >> 3;            // requires nbn % 8 == 0 (48, 16: ok)
  int wg = blockIdx.x;
  int xcd = wg & 7, g = wg >> 3;
  int bm = (g / chunk) * 128;
  int bn = (xcd * chunk + g % chunk) * 128;

  int tid = threadIdx.x;
  int wid = tid >> 6, lane = tid & 63;
  int wr = wid >> 1, wc = wid & 1;
  int fr = lane & 15, fq = lane >> 4;
  int srow = tid >> 2;              // 0..63
  int scol = (tid & 3) * 8;         // bf16 elems, 16B chunk

  f32x4 acc[4][4] = {};

  const u16* a_rd = As + (wr * 64 + fr) * 40 + fq * 8;
  const u16* b_rd = Bs + (wc * 64 + fr) * 40 + fq * 8;

  for (int k0 = 0; k0 < K; k0 += 32) {
    int4 a0 = *(const int4*)(A + (size_t)(bm + srow) * K + k0 + scol);
    int4 a1 = *(const int4*)(A + (size_t)(bm + 64 + srow) * K + k0 + scol);
    int4 b0 = *(const int4*)(BT + (size_t)(bn + srow) * K + k0 + scol);
    int4 b1 = *(const int4*)(BT + (size_t)(bn + 64 + srow) * K + k0 + scol);
    __syncthreads();
    *(int4*)(As + srow * 40 + scol) = a0;
    *(int4*)(As + (64 + srow) * 40 + scol) = a1;
    *(int4*)(Bs + srow * 40 + scol) = b0;
    *(int4*)(Bs + (64 + srow) * 40 + scol) = b1;
    __syncthreads();
    bf16x8 af[4], bfr[4];
    #pragma unroll
    for (int m = 0; m < 4; ++m) af[m]  = *(const bf16x8*)(a_rd + m * 16 * 40);
    #pragma unroll
    for (int n = 0; n < 4; ++n) bfr[n] = *(const bf16x8*)(b_rd + n * 16 * 40);
    #pragma unroll
    for (int m = 0; m < 4; ++m)
      #pragma unroll
      for (int n = 0; n < 4; ++n)
        acc[m][n] = __builtin_amdgcn_mfma_f32_16x16x32_bf16(af[m], bfr[n], acc[m][n], 0, 0, 0);
  }
  #pragma unroll
  for (int m = 0; m < 4; ++m)
    #pragma unroll
    for (int n = 0; n < 4; ++n)
      #pragma unroll
      for (int r = 0; r < 4; ++r) {
        int row = bm + wr * 64 + m * 16 + fq * 4 + r;
        int col = bn + wc * 64 + n * 16 + fr;
        C[(size_t)row * N + col] = acc[m][n][r];
      }
}

// ---------------------------------- cached_kv: one thread per output element
// [VERIFIED round 4 — do not touch]
__global__ __launch_bounds__(256) void kvout_slow(
    const float* __restrict__ qkv, float* __restrict__ cached) {
  size_t gid = (size_t)blockIdx.x * 256 + threadIdx.x;  // 16,777,216
  int d = (int)(gid & 127);
  size_t r = gid >> 7;
  int n = (int)(r & 2047); r >>= 11;
  int h = (int)(r & 15);   r >>= 4;
  int b = (int)(r & 1);    r >>= 1;
  int kv = (int)r;         // 0=k, 1=v  (pre-RoPE)
  cached[gid] = qkv[(size_t)(b * SEQ + n) * NQKV + (size_t)(1 + kv) * DIM + h * DH + d];
}

// ------------------------- RoPE cos/sin table (fp64 build, fp32 store) ------
// [VERIFIED round 10 — unchanged]
__global__ __launch_bounds__(256) void rope_table(float2* __restrict__ tab) {
  int gid = blockIdx.x * 256 + threadIdx.x;   // 131072
  int p = gid & 63;
  int n = gid >> 6;
  double inv = pow(10000.0, -(double)p / 64.0);
  double ang = (double)n * inv;
  tab[gid] = make_float2((float)cos(ang), (float)sin(ang));
}

// ------------------------------------- RoPE apply in-place (fp32, per pair) -
// [VERIFIED round 10 — unchanged]
__global__ __launch_bounds__(256) void rope_apply(float* __restrict__ qkv,
                                                  const float2* __restrict__ tab) {
  int gid = blockIdx.x * 256 + threadIdx.x;   // 8,388,608 pairs (q and k)
  int p = gid & 63;
  int n = (gid >> 6) & 2047;
  int h = (gid >> 17) & 15;
  int s = (gid >> 21) & 1;    // 0 = q, 1 = k
  int b = (gid >> 22) & 1;
  float* base = qkv + (size_t)(b * SEQ + n) * NQKV + s * DIM + h * DH + 2 * p;
  float2 cs = tab[n * 64 + p];
  float2 w = *(float2*)base;
  float2 o;
  o.x = w.x * cs.x - w.y * cs.y;
  o.y = w.y * cs.x + w.x * cs.y;
  *(float2*)base = o;
}

// ------------------------- V transpose + cast -> vT[bh][d][n] (bf16) --------
// [VERIFIED round 6 — unchanged]
__global__ void transpose_v_cast(const float* __restrict__ qkv,
                                 u16* __restrict__ vT) {
  int bh = blockIdx.z; int b = bh >> 4, h = bh & 15;
  int d0 = blockIdx.x * 32, n0 = blockIdx.y * 32;
  __shared__ float tile[32][33];
  int tx = threadIdx.x, ty = threadIdx.y;   // (32,8)
  const float* src = qkv + (size_t)(b * SEQ + n0) * NQKV + 2 * DIM + h * DH + d0;
  #pragma unroll
  for (int j = 0; j < 32; j += 8)
    tile[ty + j][tx] = src[(size_t)(ty + j) * NQKV + tx];
  __syncthreads();
  u16* dst = vT + ((size_t)bh * DH + d0) * SEQ + n0;
  #pragma unroll
  for (int j = 0; j < 32; j += 8)
    dst[(size_t)(ty + j) * SEQ + tx] = f2bf(tile[tx][ty + j]);
}

// ----------------- pack post-RoPE q,k as bf16 into the dead fp32-V region ---
// [VERIFIED round 7 — unchanged]
__global__ __launch_bounds__(256) void pack_qk(float* __restrict__ qkv) {
  int row = blockIdx.x;           // 0..4095
  int t = threadIdx.x;            // 16 elems each over q+k (4096 elems)
  const float* src = qkv + (size_t)row * NQKV + t * 16;
  float4 f0 = ((const float4*)src)[0];
  float4 f1 = ((const float4*)src)[1];
  float4 f2 = ((const float4*)src)[2];
  float4 f3 = ((const float4*)src)[3];
  union { u16 h[16]; int4 q[2]; } cv;
  cv.h[0]=f2bf(f0.x);  cv.h[1]=f2bf(f0.y);  cv.h[2]=f2bf(f0.z);  cv.h[3]=f2bf(f0.w);
  cv.h[4]=f2bf(f1.x);  cv.h[5]=f2bf(f1.y);  cv.h[6]=f2bf(f1.z);  cv.h[7]=f2bf(f1.w);
  cv.h[8]=f2bf(f2.x);  cv.h[9]=f2bf(f2.y);  cv.h[10]=f2bf(f2.z); cv.h[11]=f2bf(f2.w);
  cv.h[12]=f2bf(f3.x); cv.h[13]=f2bf(f3.y); cv.h[14]=f2bf(f3.z); cv.h[15]=f2bf(f3.w);
  u16* dst = (u16*)(qkv + (size_t)row * NQKV) + 8192 + t * 16;
  ((int4*)dst)[0] = cv.q[0];
  ((int4*)dst)[1] = cv.q[1];
}

// ------------- MFMA causal flash attention, 4 waves x 16 q-rows / block -----
// Per-wave tile body byte-identical to round 12 (K-reg prefetch, V hoist).
// Launch geometry change only: 256-thr blocks (4 waves over one 64-row tile)
// to pack 4x more waves per workgroup slot, + the round-11-validated
// XCD-sequential bh ownership: xcd = wg&7 owns bh = {x,8+x,16+x,24+x}
// sequentially, longest-qt64-first; per-XCD live set ~1.5 MB << 4 MB L2.
// No barriers: each wave owns its P_lds slice; waves drift (m114).
__global__ __launch_bounds__(256) void attn_mfma4w(
    const u16* __restrict__ qkp,   // u16 view of qkvf (packed q,k in V region)
    const u16* __restrict__ vT,    // (32,128,2048) bf16
    u16* __restrict__ ctx) {       // (4096, 2048) bf16
  int wg = blockIdx.x;             // 0..1023
  int xcd = wg & 7;
  int g   = wg >> 3;               // 0..127 within-XCD sequence
  int bh  = (g >> 5) * 8 + xcd;    // 0..31
  int qt  = 31 - (g & 31);         // 64-row tile, longest first within bh
  int b = bh >> 4, h = bh & 15;
  int tid = threadIdx.x;
  int wid = tid >> 6, lane = tid & 63;
  int fr = lane & 15, fq = lane >> 4;
  int qr0 = qt * 64 + wid * 16;

  __shared__ u16 P_lds[4][16 * 72];
  u16* Pw = &P_lds[wid][0];

  const size_t rstr = 2 * NQKV;    // u16 per row
  const u16* Qb = qkp + (size_t)(b * SEQ) * rstr + 8192 + h * 128;
  const u16* Kb = qkp + (size_t)(b * SEQ) * rstr + 10240 + h * 128;
  const u16* Vt = vT + (size_t)bh * DH * SEQ;

  bf16x8 qf[4];
  {
    const u16* qrow = Qb + (size_t)(qr0 + fr) * rstr + fq * 8;
    #pragma unroll
    for (int kk = 0; kk < 4; ++kk) qf[kk] = *(const bf16x8*)(qrow + kk * 32);
  }

  f32x4 acc[8] = {};
  float m_r[4], l_r[4];
  #pragma unroll
  for (int r = 0; r < 4; ++r) { m_r[r] = -3e38f; l_r[r] = 0.f; }

  const float scale = 0.08838834764831845f;
  int i0 = qr0 + fq * 4;
  int jt_end = qt;                 // (qr0+15)>>6 == qt for all 4 waves

  bf16x8 kreg[16];   // [jf][kk]
  bf16x8 vreg[16];   // [df][half]

  // preload K tile 0
  #pragma unroll
  for (int jf = 0; jf < 4; ++jf) {
    const u16* krow = Kb + (size_t)(jf * 16 + fr) * rstr + fq * 8;
    #pragma unroll
    for (int kk = 0; kk < 4; ++kk) kreg[jf * 4 + kk] = *(const bf16x8*)(krow + kk * 32);
  }

  for (int jt = 0; jt <= jt_end; ++jt) {
    int j0 = jt * 64;

    // issue V loads for THIS tile now — consumed after softmax
    #pragma unroll
    for (int df = 0; df < 8; ++df) {
      const u16* vrow = Vt + (size_t)(df * 16 + fr) * SEQ + j0 + fq * 8;
      vreg[df * 2]     = *(const bf16x8*)(vrow);
      vreg[df * 2 + 1] = *(const bf16x8*)(vrow + 32);
    }

    // QK^T from register-resident K
    f32x4 s[4];
    #pragma unroll
    for (int jf = 0; jf < 4; ++jf) {
      f32x4 sa = {0.f, 0.f, 0.f, 0.f};
      #pragma unroll
      for (int kk = 0; kk < 4; ++kk)
        sa = __builtin_amdgcn_mfma_f32_16x16x32_bf16(qf[kk], kreg[jf * 4 + kk], sa, 0, 0, 0);
      s[jf] = sa;
    }

    // prefetch NEXT K tile into the same (now dead) registers
    if (jt < jt_end) {
      int jn0 = j0 + 64;
      #pragma unroll
      for (int jf = 0; jf < 4; ++jf) {
        const u16* krow = Kb + (size_t)(jn0 + jf * 16 + fr) * rstr + fq * 8;
        #pragma unroll
        for (int kk = 0; kk < 4; ++kk) kreg[jf * 4 + kk] = *(const bf16x8*)(krow + kk * 32);
      }
    }

    #pragma unroll
    for (int jf = 0; jf < 4; ++jf) {
      int j = j0 + jf * 16 + fr;
      #pragma unroll
      for (int r = 0; r < 4; ++r) {
        float v = s[jf][r] * scale;
        s[jf][r] = (j > i0 + r) ? -1e30f : v;
      }
    }
    float al[4], ls[4];
    #pragma unroll
    for (int r = 0; r < 4; ++r) {
      float mx = fmaxf(fmaxf(s[0][r], s[1][r]), fmaxf(s[2][r], s[3][r]));
      #pragma unroll
      for (int off = 8; off >= 1; off >>= 1) mx = fmaxf(mx, __shfl_xor(mx, off));
      float mn = fmaxf(m_r[r], mx);
      al[r] = __expf(m_r[r] - mn);
      m_r[r] = mn;
      float sum = 0.f;
      #pragma unroll
      for (int jf = 0; jf < 4; ++jf) {
        float p = __expf(s[jf][r] - mn);
        s[jf][r] = p;
        sum += p;
      }
      #pragma unroll
      for (int off = 8; off >= 1; off >>= 1) sum += __shfl_xor(sum, off);
      ls[r] = sum;
    }
    #pragma unroll
    for (int jf = 0; jf < 4; ++jf)
      #pragma unroll
      for (int r = 0; r < 4; ++r)
        Pw[(fq * 4 + r) * 72 + jf * 16 + fr] = f2bf(s[jf][r]);
    #pragma unroll
    for (int r = 0; r < 4; ++r) l_r[r] = l_r[r] * al[r] + ls[r];
    #pragma unroll
    for (int df = 0; df < 8; ++df)
      #pragma unroll
      for (int r = 0; r < 4; ++r) acc[df][r] *= al[r];

    bf16x8 pa0 = *(const bf16x8*)(Pw + fr * 72 + fq * 8);
    bf16x8 pa1 = *(const bf16x8*)(Pw + fr * 72 + 32 + fq * 8);
    #pragma unroll
    for (int df = 0; df < 8; ++df) {
      acc[df] = __builtin_amdgcn_mfma_f32_16x16x32_bf16(pa0, vreg[df * 2],     acc[df], 0, 0, 0);
      acc[df] = __builtin_amdgcn_mfma_f32_16x16x32_bf16(pa1, vreg[df * 2 + 1], acc[df], 0, 0, 0);
    }
  }
  #pragma unroll
  for (int df = 0; df < 8; ++df)
    #pragma unroll
    for (int r = 0; r < 4; ++r) {
      int i = qr0 + fq * 4 + r;
      int d = df * 16 + fr;
      ctx[(size_t)(b * SEQ + i) * DIM + h * DH + d] = f2bf(acc[df][r] / l_r[r]);
    }
}

// ----------------------------------------------------------------- launch ---
extern "C" void kernel_launch(void* const* d_in, const int* in_sizes, int n_in,
                              void* d_out, int out_size, void* d_ws, size_t ws_size,
                              hipStream_t stream) {
  // size-keyed input selection (sizes are pairwise distinct)
  const float *x = nullptr, *gamma = nullptr, *wq = nullptr, *wo = nullptr;
  for (int ii = 0; ii < n_in; ++ii) {
    switch (in_sizes[ii]) {
      case  8388608: x     = (const float*)d_in[ii]; break;
      case     2048: gamma = (const float*)d_in[ii]; break;
      case 12582912: wq    = (const float*)d_in[ii]; break;
      case  4194304: wo    = (const float*)d_in[ii]; break;
    }
  }
  if (!x || !gamma || !wq || !wo) {   // fallback: documented dict order
    x = (const float*)d_in[0]; gamma = (const float*)d_in[1];
    wq = (const float*)d_in[2]; wo = (const float*)d_in[3];
  }

  float* out    = (float*)d_out;           // (2,2048,2048) = first 33.55 MB
  float* cached = out + 8388608;           // (2,2,16,2048,128) at byte 33.55M

  // ws (134.2 MB, proven footprint), time-multiplexed:
  //   [0, 25.2M)       xn(head) -> wqkvT -> ctx(first 16.8M)
  //   [25.2M, 33.55M)  xn(tail) -> woutT (live until final GEMM)
  //   [33.55M, 134.2M) qkvf (fp32; V third repurposed for packed bf16 q,k)
  // out-region scratch (dead before final GEMM writes out):
  //   out[0, 16.8M)    xnb (bf16 A) -> vT (bf16) after QKV GEMM
  //   out[16.8M,17.8M) rope table
  float* xn    = (float*)d_ws;
  u16*   wqkvT = (u16*)d_ws;
  u16*   ctx   = (u16*)d_ws;
  u16*   woutT = (u16*)((char*)d_ws + 25165824);
  float* qkvf  = (float*)((char*)d_ws + 33554432);
  u16*   xnb   = (u16*)d_out;
  u16*   vT    = (u16*)d_out;
  float2* tab  = (float2*)((char*)d_out + 16777216);

  rms_slow<<<ROWS, 64, 0, stream>>>(x, gamma, xn);
  rope_table<<<131072 / 256, 256, 0, stream>>>(tab);
  cast_bf16<<<4096, 256, 0, stream>>>(xn, xnb);                 // xn dead after
  transpose_f32_bf16<<<dim3(NQKV / 32, DIM / 32), dim3(32, 8), 0, stream>>>(wq, wqkvT, DIM, NQKV);
  transpose_f32_bf16<<<dim3(DIM / 32, DIM / 32), dim3(32, 8), 0, stream>>>(wo, woutT, DIM, DIM);
  gemm_nt<<<(ROWS / 128) * (NQKV / 128), 256, 0, stream>>>(xnb, wqkvT, qkvf, ROWS, NQKV, DIM);
  kvout_slow<<<65536, 256, 0, stream>>>(qkvf, cached);
  rope_apply<<<32768, 256, 0, stream>>>(qkvf, tab);
  transpose_v_cast<<<dim3(DH / 32, SEQ / 32, 32), dim3(32, 8), 0, stream>>>(qkvf, vT);  // overwrites dead xnb
  pack_qk<<<ROWS, 256, 0, stream>>>(qkvf);
  attn_mfma4w<<<1024, 256, 0, stream>>>((const u16*)qkvf, vT, ctx);   // ctx overwrites dead wqkvT
  gemm_nt<<<(ROWS / 128) * (DIM / 128), 256, 0, stream>>>(ctx, woutT, out, ROWS, DIM, DIM);
}

// Round 14
// 599.807 us; speedup vs baseline: 1.0027x; 1.0027x over previous
//
#include <hip/hip_runtime.h>
#include <cstdint>
#include <cstddef>
#include <math.h>

#define SEQ   2048
#define DIM   2048
#define NQKV  6144
#define NH    16
#define DH    128
#define ROWS  4096   /* b*n */

typedef unsigned short u16;
typedef unsigned int u32;
typedef __attribute__((ext_vector_type(8))) short bf16x8;
typedef __attribute__((ext_vector_type(4))) float f32x4;

__device__ __forceinline__ u16 f2bf(float f) {
  union { float f; u32 u; } v;
  v.f = f;
  u32 r = v.u + 0x7FFFu + ((v.u >> 16) & 1u);
  return (u16)(r >> 16);
}

// ------------------------------------------------ rmsnorm (fp64, 1 wave/row)
// [VERIFIED round 4 — do not touch]
__global__ __launch_bounds__(64) void rms_slow(
    const float* __restrict__ x, const float* __restrict__ g,
    float* __restrict__ xn) {
  int row = blockIdx.x, lane = threadIdx.x;
  const float* xr = x + (size_t)row * DIM;
  double ss = 0.0;
  for (int c = lane; c < DIM; c += 64) { double v = xr[c]; ss += v * v; }
  #pragma unroll
  for (int off = 32; off >= 1; off >>= 1) ss += __shfl_xor(ss, off);
  double nrm = sqrt(ss); if (nrm < 1e-12) nrm = 1e-12;
  double sc = 45.254833995939045 / nrm;   // sqrt(2048)/||x||
  float* dst = xn + (size_t)row * DIM;
  for (int c = lane; c < DIM; c += 64) dst[c] = (float)((double)xr[c] * sc * (double)g[c]);
}

// ----------------------------------------- fp32 -> bf16 cast (8 elems/thread)
// [VERIFIED round 12 — unchanged]
__global__ __launch_bounds__(256) void cast_bf16(
    const float* __restrict__ in, u16* __restrict__ out) {
  size_t i = ((size_t)blockIdx.x * 256 + threadIdx.x) * 8;
  float4 f0 = *(const float4*)(in + i);
  float4 f1 = *(const float4*)(in + i + 4);
  union { u16 h[8]; int4 q; } cv;
  cv.h[0]=f2bf(f0.x); cv.h[1]=f2bf(f0.y); cv.h[2]=f2bf(f0.z); cv.h[3]=f2bf(f0.w);
  cv.h[4]=f2bf(f1.x); cv.h[5]=f2bf(f1.y); cv.h[6]=f2bf(f1.z); cv.h[7]=f2bf(f1.w);
  *(int4*)(out + i) = cv.q;
}

// ------------------------------------------------- fp32 -> bf16 transpose ---
// [VERIFIED round 12 — unchanged]
__global__ void transpose_f32_bf16(const float* __restrict__ in,
                                   u16* __restrict__ out, int R, int C) {
  __shared__ float tile[32][33];
  int bx = blockIdx.x * 32;   // C index
  int by = blockIdx.y * 32;   // R index
  int tx = threadIdx.x, ty = threadIdx.y;   // (32,8)
  #pragma unroll
  for (int j = 0; j < 32; j += 8)
    tile[ty + j][tx] = in[(size_t)(by + ty + j) * C + bx + tx];
  __syncthreads();
  #pragma unroll
  for (int j = 0; j < 32; j += 8)
    out[(size_t)(bx + ty + j) * R + by + tx] = f2bf(tile[tx][ty + j]);
}

// ------------------------------------------ bf16 NT GEMM, XCD-swizzled ------
// [VERIFIED round 12 — unchanged]
__global__ __launch_bounds__(256) void gemm_nt(
    const u16* __restrict__ A, const u16* __restrict__ BT,
    float* __restrict__ C, int M, int N, int K) {
  __shared__ u16 As[128 * 40];
  __shared__ u16 Bs[128 * 40];
  int nbn = N >> 7;
  int chunk = nbn >> 3;            // requires nbn % 8 == 0 (48, 16: ok)
  int wg = blockIdx.x;
  int xcd = wg & 7, g = wg >> 3;
  int bm = (g / chunk) * 128;
  int bn = (xcd * chunk + g % chunk) * 128;

  int tid = threadIdx.x;
  int wid = tid >> 6, lane = tid & 63;
  int wr = wid >> 1, wc = wid & 1;
  int fr = lane & 15, fq = lane >> 4;
  int srow = tid >> 2;              // 0..63
  int scol = (tid & 3) * 8;         // bf16 elems, 16B chunk

  f32x4 acc[4][4] = {};

  const u16* a_rd = As + (wr * 64 + fr) * 40 + fq * 8;
  const u16* b_rd = Bs + (wc * 64 + fr) * 40 + fq * 8;

  for (int k0 = 0; k0 < K; k0 += 32) {
    int4 a0 = *(const int4*)(A + (size_t)(bm + srow) * K + k0 + scol);
    int4 a1 = *(const int4*)(A + (size_t)(bm + 64 + srow) * K + k0 + scol);
    int4 b0 = *(const int4*)(BT + (size_t)(bn + srow) * K + k0 + scol);
    int4 b1 = *(const int4*)(BT + (size_t)(bn + 64 + srow) * K + k0 + scol);
    __syncthreads();
    *(int4*)(As + srow * 40 + scol) = a0;
    *(int4*)(As + (64 + srow) * 40 + scol) = a1;
    *(int4*)(Bs + srow * 40 + scol) = b0;
    *(int4*)(Bs + (64 + srow) * 40 + scol) = b1;
    __syncthreads();
    bf16x8 af[4], bfr[4];
    #pragma unroll
    for (int m = 0; m < 4; ++m) af[m]  = *(const bf16x8*)(a_rd + m * 16 * 40);
    #pragma unroll
    for (int n = 0; n < 4; ++n) bfr[n] = *(const bf16x8*)(b_rd + n * 16 * 40);
    #pragma unroll
    for (int m = 0; m < 4; ++m)
      #pragma unroll
      for (int n = 0; n < 4; ++n)
        acc[m][n] = __builtin_amdgcn_mfma_f32_16x16x32_bf16(af[m], bfr[n], acc[m][n], 0, 0, 0);
  }
  #pragma unroll
  for (int m = 0; m < 4; ++m)
    #pragma unroll
    for (int n = 0; n < 4; ++n)
      #pragma unroll
      for (int r = 0; r < 4; ++r) {
        int row = bm + wr * 64 + m * 16 + fq * 4 + r;
        int col = bn + wc * 64 + n * 16 + fr;
        C[(size_t)row * N + col] = acc[m][n][r];
      }
}

// ---------------------------------- cached_kv: one thread per output element
// [VERIFIED round 4 — do not touch]
__global__ __launch_bounds__(256) void kvout_slow(
    const float* __restrict__ qkv, float* __restrict__ cached) {
  size_t gid = (size_t)blockIdx.x * 256 + threadIdx.x;  // 16,777,216
  int d = (int)(gid & 127);
  size_t r = gid >> 7;
  int n = (int)(r & 2047); r >>= 11;
  int h = (int)(r & 15);   r >>= 4;
  int b = (int)(r & 1);    r >>= 1;
  int kv = (int)r;         // 0=k, 1=v  (pre-RoPE)
  cached[gid] = qkv[(size_t)(b * SEQ + n) * NQKV + (size_t)(1 + kv) * DIM + h * DH + d];
}

// ------------------------- RoPE cos/sin table (fp64 build, fp32 store) ------
// [VERIFIED round 10 — unchanged]
__global__ __launch_bounds__(256) void rope_table(float2* __restrict__ tab) {
  int gid = blockIdx.x * 256 + threadIdx.x;   // 131072
  int p = gid & 63;
  int n = gid >> 6;
  double inv = pow(10000.0, -(double)p / 64.0);
  double ang = (double)n * inv;
  tab[gid] = make_float2((float)cos(ang), (float)sin(ang));
}

// ------------------------------------- RoPE apply in-place (fp32, per pair) -
// [VERIFIED round 10 — unchanged]
__global__ __launch_bounds__(256) void rope_apply(float* __restrict__ qkv,
                                                  const float2* __restrict__ tab) {
  int gid = blockIdx.x * 256 + threadIdx.x;   // 8,388,608 pairs (q and k)
  int p = gid & 63;
  int n = (gid >> 6) & 2047;
  int h = (gid >> 17) & 15;
  int s = (gid >> 21) & 1;    // 0 = q, 1 = k
  int b = (gid >> 22) & 1;
  float* base = qkv + (size_t)(b * SEQ + n) * NQKV + s * DIM + h * DH + 2 * p;
  float2 cs = tab[n * 64 + p];
  float2 w = *(float2*)base;
  float2 o;
  o.x = w.x * cs.x - w.y * cs.y;
  o.y = w.y * cs.x + w.x * cs.y;
  *(float2*)base = o;
}

// ------------------------- V transpose + cast -> vT[bh][d][n] (bf16) --------
// [VERIFIED round 6 — unchanged]
__global__ void transpose_v_cast(const float* __restrict__ qkv,
                                 u16* __restrict__ vT) {
  int bh = blockIdx.z; int b = bh >> 4, h = bh & 15;
  int d0 = blockIdx.x * 32, n0 = blockIdx.y * 32;
  __shared__ float tile[32][33];
  int tx = threadIdx.x, ty = threadIdx.y;   // (32,8)
  const float* src = qkv + (size_t)(b * SEQ + n0) * NQKV + 2 * DIM + h * DH + d0;
  #pragma unroll
  for (int j = 0; j < 32; j += 8)
    tile[ty + j][tx] = src[(size_t)(ty + j) * NQKV + tx];
  __syncthreads();
  u16* dst = vT + ((size_t)bh * DH + d0) * SEQ + n0;
  #pragma unroll
  for (int j = 0; j < 32; j += 8)
    dst[(size_t)(ty + j) * SEQ + tx] = f2bf(tile[tx][ty + j]);
}

// ----------------- pack post-RoPE q,k as bf16 into the dead fp32-V region ---
// [VERIFIED round 7 — unchanged]
__global__ __launch_bounds__(256) void pack_qk(float* __restrict__ qkv) {
  int row = blockIdx.x;           // 0..4095
  int t = threadIdx.x;            // 16 elems each over q+k (4096 elems)
  const float* src = qkv + (size_t)row * NQKV + t * 16;
  float4 f0 = ((const float4*)src)[0];
  float4 f1 = ((const float4*)src)[1];
  float4 f2 = ((const float4*)src)[2];
  float4 f3 = ((const float4*)src)[3];
  union { u16 h[16]; int4 q[2]; } cv;
  cv.h[0]=f2bf(f0.x);  cv.h[1]=f2bf(f0.y);  cv.h[2]=f2bf(f0.z);  cv.h[3]=f2bf(f0.w);
  cv.h[4]=f2bf(f1.x);  cv.h[5]=f2bf(f1.y);  cv.h[6]=f2bf(f1.z);  cv.h[7]=f2bf(f1.w);
  cv.h[8]=f2bf(f2.x);  cv.h[9]=f2bf(f2.y);  cv.h[10]=f2bf(f2.z); cv.h[11]=f2bf(f2.w);
  cv.h[12]=f2bf(f3.x); cv.h[13]=f2bf(f3.y); cv.h[14]=f2bf(f3.z); cv.h[15]=f2bf(f3.w);
  u16* dst = (u16*)(qkv + (size_t)row * NQKV) + 8192 + t * 16;
  ((int4*)dst)[0] = cv.q[0];
  ((int4*)dst)[1] = cv.q[1];
}

// ------ MFMA causal flash attention, 1 wave / 16 q-rows, KVBLK=128 ----------
// Round-12 kernel with the KV loop widened to 128 columns per iteration:
// one online-softmax update (max/sum/rescale/P-roundtrip/loop overhead) now
// amortizes over TWO 64-wide KV tiles. K loaded in two halves reusing kreg;
// V half-1 hoisted above softmax (hidden); V half-2 issued before PV half-1
// (hidden under PV half-1). Masking formula identical; fully-masked second
// halves on diagonal tiles compute exp->0 harmlessly (~3% waste, uniform).
// XCD-sequential bh ownership decode identical to round 11/12.
__global__ __launch_bounds__(64) void attn_mfma16(
    const u16* __restrict__ qkp,   // u16 view of qkvf (packed q,k in V region)
    const u16* __restrict__ vT,    // (32,128,2048) bf16
    u16* __restrict__ ctx) {       // (4096, 2048) bf16
  int wg = blockIdx.x;             // 0..4095
  int xcd = wg & 7;
  int g   = wg >> 3;               // 0..511 within-XCD sequence
  int bh  = (g >> 7) * 8 + xcd;    // 0..31
  int qt  = 127 - (g & 127);       // longest blocks first within each bh
  int b = bh >> 4, h = bh & 15;
  int lane = threadIdx.x;
  int fr = lane & 15, fq = lane >> 4;
  int qr0 = qt * 16;

  __shared__ u16 Pw[16 * 136];     // 128 j's + 8 pad per q-row

  const size_t rstr = 2 * NQKV;    // u16 per row
  const u16* Qb = qkp + (size_t)(b * SEQ) * rstr + 8192 + h * 128;
  const u16* Kb = qkp + (size_t)(b * SEQ) * rstr + 10240 + h * 128;
  const u16* Vt = vT + (size_t)bh * DH * SEQ;

  bf16x8 qf[4];
  {
    const u16* qrow = Qb + (size_t)(qr0 + fr) * rstr + fq * 8;
    #pragma unroll
    for (int kk = 0; kk < 4; ++kk) qf[kk] = *(const bf16x8*)(qrow + kk * 32);
  }

  f32x4 acc[8] = {};
  float m_r[4], l_r[4];
  #pragma unroll
  for (int r = 0; r < 4; ++r) { m_r[r] = -3e38f; l_r[r] = 0.f; }

  const float scale = 0.08838834764831845f;
  int i0 = qr0 + fq * 4;
  int jt_end = qt >> 3;            // 128-wide tiles covering j <= qr0+15

  bf16x8 kreg[16];   // one 64-half of K, reused
  bf16x8 vreg[16];   // one 64-half of V, reused

  for (int jt = 0; jt <= jt_end; ++jt) {
    int j0 = jt * 128;
    f32x4 s[8];

    // ---- K half 1 -> QK s[0..3]
    #pragma unroll
    for (int jf = 0; jf < 4; ++jf) {
      const u16* krow = Kb + (size_t)(j0 + jf * 16 + fr) * rstr + fq * 8;
      #pragma unroll
      for (int kk = 0; kk < 4; ++kk) kreg[jf * 4 + kk] = *(const bf16x8*)(krow + kk * 32);
    }
    #pragma unroll
    for (int jf = 0; jf < 4; ++jf) {
      f32x4 sa = {0.f, 0.f, 0.f, 0.f};
      #pragma unroll
      for (int kk = 0; kk < 4; ++kk)
        sa = __builtin_amdgcn_mfma_f32_16x16x32_bf16(qf[kk], kreg[jf * 4 + kk], sa, 0, 0, 0);
      s[jf] = sa;
    }

    // ---- V half 1 loads (consumed after softmax — hidden)
    #pragma unroll
    for (int df = 0; df < 8; ++df) {
      const u16* vrow = Vt + (size_t)(df * 16 + fr) * SEQ + j0 + fq * 8;
      vreg[df * 2]     = *(const bf16x8*)(vrow);
      vreg[df * 2 + 1] = *(const bf16x8*)(vrow + 32);
    }

    // ---- K half 2 -> QK s[4..7] (kreg reused)
    #pragma unroll
    for (int jf = 0; jf < 4; ++jf) {
      const u16* krow = Kb + (size_t)(j0 + 64 + jf * 16 + fr) * rstr + fq * 8;
      #pragma unroll
      for (int kk = 0; kk < 4; ++kk) kreg[jf * 4 + kk] = *(const bf16x8*)(krow + kk * 32);
    }
    #pragma unroll
    for (int jf = 0; jf < 4; ++jf) {
      f32x4 sa = {0.f, 0.f, 0.f, 0.f};
      #pragma unroll
      for (int kk = 0; kk < 4; ++kk)
        sa = __builtin_amdgcn_mfma_f32_16x16x32_bf16(qf[kk], kreg[jf * 4 + kk], sa, 0, 0, 0);
      s[4 + jf] = sa;
    }

    // ---- mask (same formula, 8 fragments)
    #pragma unroll
    for (int jf = 0; jf < 8; ++jf) {
      int j = j0 + jf * 16 + fr;
      #pragma unroll
      for (int r = 0; r < 4; ++r) {
        float v = s[jf][r] * scale;
        s[jf][r] = (j > i0 + r) ? -1e30f : v;
      }
    }

    // ---- ONE online-softmax update for all 128 columns
    float al[4], ls[4];
    #pragma unroll
    for (int r = 0; r < 4; ++r) {
      float mx = s[0][r];
      #pragma unroll
      for (int jf = 1; jf < 8; ++jf) mx = fmaxf(mx, s[jf][r]);
      #pragma unroll
      for (int off = 8; off >= 1; off >>= 1) mx = fmaxf(mx, __shfl_xor(mx, off));
      float mn = fmaxf(m_r[r], mx);
      al[r] = __expf(m_r[r] - mn);
      m_r[r] = mn;
      float sum = 0.f;
      #pragma unroll
      for (int jf = 0; jf < 8; ++jf) {
        float p = __expf(s[jf][r] - mn);
        s[jf][r] = p;
        sum += p;
      }
      #pragma unroll
      for (int off = 8; off >= 1; off >>= 1) sum += __shfl_xor(sum, off);
      ls[r] = sum;
    }
    #pragma unroll
    for (int jf = 0; jf < 8; ++jf)
      #pragma unroll
      for (int r = 0; r < 4; ++r)
        Pw[(fq * 4 + r) * 136 + jf * 16 + fr] = f2bf(s[jf][r]);
    #pragma unroll
    for (int r = 0; r < 4; ++r) l_r[r] = l_r[r] * al[r] + ls[r];
    #pragma unroll
    for (int df = 0; df < 8; ++df)
      #pragma unroll
      for (int r = 0; r < 4; ++r) acc[df][r] *= al[r];

    // ---- PV half 1 (V already in regs)
    bf16x8 pa0 = *(const bf16x8*)(Pw + fr * 136 + fq * 8);
    bf16x8 pa1 = *(const bf16x8*)(Pw + fr * 136 + 32 + fq * 8);
    bf16x8 pa2 = *(const bf16x8*)(Pw + fr * 136 + 64 + fq * 8);
    bf16x8 pa3 = *(const bf16x8*)(Pw + fr * 136 + 96 + fq * 8);
    #pragma unroll
    for (int df = 0; df < 8; ++df) {
      acc[df] = __builtin_amdgcn_mfma_f32_16x16x32_bf16(pa0, vreg[df * 2],     acc[df], 0, 0, 0);
      acc[df] = __builtin_amdgcn_mfma_f32_16x16x32_bf16(pa1, vreg[df * 2 + 1], acc[df], 0, 0, 0);
    }

    // ---- V half 2 loads + PV half 2 (loads overlap PV half 1 issue above)
    #pragma unroll
    for (int df = 0; df < 8; ++df) {
      const u16* vrow = Vt + (size_t)(df * 16 + fr) * SEQ + j0 + 64 + fq * 8;
      vreg[df * 2]     = *(const bf16x8*)(vrow);
      vreg[df * 2 + 1] = *(const bf16x8*)(vrow + 32);
    }
    #pragma unroll
    for (int df = 0; df < 8; ++df) {
      acc[df] = __builtin_amdgcn_mfma_f32_16x16x32_bf16(pa2, vreg[df * 2],     acc[df], 0, 0, 0);
      acc[df] = __builtin_amdgcn_mfma_f32_16x16x32_bf16(pa3, vreg[df * 2 + 1], acc[df], 0, 0, 0);
    }
  }
  #pragma unroll
  for (int df = 0; df < 8; ++df)
    #pragma unroll
    for (int r = 0; r < 4; ++r) {
      int i = qr0 + fq * 4 + r;
      int d = df * 16 + fr;
      ctx[(size_t)(b * SEQ + i) * DIM + h * DH + d] = f2bf(acc[df][r] / l_r[r]);
    }
}

// ----------------------------------------------------------------- launch ---
extern "C" void kernel_launch(void* const* d_in, const int* in_sizes, int n_in,
                              void* d_out, int out_size, void* d_ws, size_t ws_size,
                              hipStream_t stream) {
  // size-keyed input selection (sizes are pairwise distinct)
  const float *x = nullptr, *gamma = nullptr, *wq = nullptr, *wo = nullptr;
  for (int ii = 0; ii < n_in; ++ii) {
    switch (in_sizes[ii]) {
      case  8388608: x     = (const float*)d_in[ii]; break;
      case     2048: gamma = (const float*)d_in[ii]; break;
      case 12582912: wq    = (const float*)d_in[ii]; break;
      case  4194304: wo    = (const float*)d_in[ii]; break;
    }
  }
  if (!x || !gamma || !wq || !wo) {   // fallback: documented dict order
    x = (const float*)d_in[0]; gamma = (const float*)d_in[1];
    wq = (const float*)d_in[2]; wo = (const float*)d_in[3];
  }

  float* out    = (float*)d_out;           // (2,2048,2048) = first 33.55 MB
  float* cached = out + 8388608;           // (2,2,16,2048,128) at byte 33.55M

  // ws (134.2 MB, proven footprint), time-multiplexed:
  //   [0, 25.2M)       xn(head) -> wqkvT -> ctx(first 16.8M)
  //   [25.2M, 33.55M)  xn(tail) -> woutT (live until final GEMM)
  //   [33.55M, 134.2M) qkvf (fp32; V third repurposed for packed bf16 q,k)
  // out-region scratch (dead before final GEMM writes out):
  //   out[0, 16.8M)    xnb (bf16 A) -> vT (bf16) after QKV GEMM
  //   out[16.8M,17.8M) rope table
  float* xn    = (float*)d_ws;
  u16*   wqkvT = (u16*)d_ws;
  u16*   ctx   = (u16*)d_ws;
  u16*   woutT = (u16*)((char*)d_ws + 25165824);
  float* qkvf  = (float*)((char*)d_ws + 33554432);
  u16*   xnb   = (u16*)d_out;
  u16*   vT    = (u16*)d_out;
  float2* tab  = (float2*)((char*)d_out + 16777216);

  rms_slow<<<ROWS, 64, 0, stream>>>(x, gamma, xn);
  rope_table<<<131072 / 256, 256, 0, stream>>>(tab);
  cast_bf16<<<4096, 256, 0, stream>>>(xn, xnb);                 // xn dead after
  transpose_f32_bf16<<<dim3(NQKV / 32, DIM / 32), dim3(32, 8), 0, stream>>>(wq, wqkvT, DIM, NQKV);
  transpose_f32_bf16<<<dim3(DIM / 32, DIM / 32), dim3(32, 8), 0, stream>>>(wo, woutT, DIM, DIM);
  gemm_nt<<<(ROWS / 128) * (NQKV / 128), 256, 0, stream>>>(xnb, wqkvT, qkvf, ROWS, NQKV, DIM);
  kvout_slow<<<65536, 256, 0, stream>>>(qkvf, cached);
  rope_apply<<<32768, 256, 0, stream>>>(qkvf, tab);
  transpose_v_cast<<<dim3(DH / 32, SEQ / 32, 32), dim3(32, 8), 0, stream>>>(qkvf, vT);  // overwrites dead xnb
  pack_qk<<<ROWS, 256, 0, stream>>>(qkvf);
  attn_mfma16<<<4096, 64, 0, stream>>>((const u16*)qkvf, vT, ctx);   // ctx overwrites dead wqkvT
  gemm_nt<<<(ROWS / 128) * (DIM / 128), 256, 0, stream>>>(ctx, woutT, out, ROWS, DIM, DIM);
}

// Round 15
// 514.128 us; speedup vs baseline: 1.1698x; 1.1666x over previous
//
#include <hip/hip_runtime.h>
#include <cstdint>
#include <cstddef>
#include <math.h>

#define SEQ   2048
#define DIM   2048
#define NQKV  6144
#define NH    16
#define DH    128
#define ROWS  4096   /* b*n */

typedef unsigned short u16;
typedef unsigned int u32;
typedef __attribute__((ext_vector_type(8))) short bf16x8;
typedef __attribute__((ext_vector_type(4))) float f32x4;
typedef __attribute__((ext_vector_type(16))) float f32x16;

__device__ __forceinline__ u16 f2bf(float f) {
  union { float f; u32 u; } v;
  v.f = f;
  u32 r = v.u + 0x7FFFu + ((v.u >> 16) & 1u);
  return (u16)(r >> 16);
}

// ------------------------------------------------ rmsnorm (fp64, 1 wave/row)
// [VERIFIED round 4 — do not touch]
__global__ __launch_bounds__(64) void rms_slow(
    const float* __restrict__ x, const float* __restrict__ g,
    float* __restrict__ xn) {
  int row = blockIdx.x, lane = threadIdx.x;
  const float* xr = x + (size_t)row * DIM;
  double ss = 0.0;
  for (int c = lane; c < DIM; c += 64) { double v = xr[c]; ss += v * v; }
  #pragma unroll
  for (int off = 32; off >= 1; off >>= 1) ss += __shfl_xor(ss, off);
  double nrm = sqrt(ss); if (nrm < 1e-12) nrm = 1e-12;
  double sc = 45.254833995939045 / nrm;   // sqrt(2048)/||x||
  float* dst = xn + (size_t)row * DIM;
  for (int c = lane; c < DIM; c += 64) dst[c] = (float)((double)xr[c] * sc * (double)g[c]);
}

// ----------------------------------------- fp32 -> bf16 cast (8 elems/thread)
// [VERIFIED round 12 — unchanged]
__global__ __launch_bounds__(256) void cast_bf16(
    const float* __restrict__ in, u16* __restrict__ out) {
  size_t i = ((size_t)blockIdx.x * 256 + threadIdx.x) * 8;
  float4 f0 = *(const float4*)(in + i);
  float4 f1 = *(const float4*)(in + i + 4);
  union { u16 h[8]; int4 q; } cv;
  cv.h[0]=f2bf(f0.x); cv.h[1]=f2bf(f0.y); cv.h[2]=f2bf(f0.z); cv.h[3]=f2bf(f0.w);
  cv.h[4]=f2bf(f1.x); cv.h[5]=f2bf(f1.y); cv.h[6]=f2bf(f1.z); cv.h[7]=f2bf(f1.w);
  *(int4*)(out + i) = cv.q;
}

// ------------------------------------------------- fp32 -> bf16 transpose ---
// [VERIFIED round 12 — unchanged]
__global__ void transpose_f32_bf16(const float* __restrict__ in,
                                   u16* __restrict__ out, int R, int C) {
  __shared__ float tile[32][33];
  int bx = blockIdx.x * 32;   // C index
  int by = blockIdx.y * 32;   // R index
  int tx = threadIdx.x, ty = threadIdx.y;   // (32,8)
  #pragma unroll
  for (int j = 0; j < 32; j += 8)
    tile[ty + j][tx] = in[(size_t)(by + ty + j) * C + bx + tx];
  __syncthreads();
  #pragma unroll
  for (int j = 0; j < 32; j += 8)
    out[(size_t)(bx + ty + j) * R + by + tx] = f2bf(tile[tx][ty + j]);
}

// ------------------------------------------ bf16 NT GEMM, XCD-swizzled ------
// [VERIFIED round 12 — unchanged]
__global__ __launch_bounds__(256) void gemm_nt(
    const u16* __restrict__ A, const u16* __restrict__ BT,
    float* __restrict__ C, int M, int N, int K) {
  __shared__ u16 As[128 * 40];
  __shared__ u16 Bs[128 * 40];
  int nbn = N >> 7;
  int chunk = nbn >> 3;            // requires nbn % 8 == 0 (48, 16: ok)
  int wg = blockIdx.x;
  int xcd = wg & 7, g = wg >> 3;
  int bm = (g / chunk) * 128;
  int bn = (xcd * chunk + g % chunk) * 128;

  int tid = threadIdx.x;
  int wid = tid >> 6, lane = tid & 63;
  int wr = wid >> 1, wc = wid & 1;
  int fr = lane & 15, fq = lane >> 4;
  int srow = tid >> 2;              // 0..63
  int scol = (tid & 3) * 8;         // bf16 elems, 16B chunk

  f32x4 acc[4][4] = {};

  const u16* a_rd = As + (wr * 64 + fr) * 40 + fq * 8;
  const u16* b_rd = Bs + (wc * 64 + fr) * 40 + fq * 8;

  for (int k0 = 0; k0 < K; k0 += 32) {
    int4 a0 = *(const int4*)(A + (size_t)(bm + srow) * K + k0 + scol);
    int4 a1 = *(const int4*)(A + (size_t)(bm + 64 + srow) * K + k0 + scol);
    int4 b0 = *(const int4*)(BT + (size_t)(bn + srow) * K + k0 + scol);
    int4 b1 = *(const int4*)(BT + (size_t)(bn + 64 + srow) * K + k0 + scol);
    __syncthreads();
    *(int4*)(As + srow * 40 + scol) = a0;
    *(int4*)(As + (64 + srow) * 40 + scol) = a1;
    *(int4*)(Bs + srow * 40 + scol) = b0;
    *(int4*)(Bs + (64 + srow) * 40 + scol) = b1;
    __syncthreads();
    bf16x8 af[4], bfr[4];
    #pragma unroll
    for (int m = 0; m < 4; ++m) af[m]  = *(const bf16x8*)(a_rd + m * 16 * 40);
    #pragma unroll
    for (int n = 0; n < 4; ++n) bfr[n] = *(const bf16x8*)(b_rd + n * 16 * 40);
    #pragma unroll
    for (int m = 0; m < 4; ++m)
      #pragma unroll
      for (int n = 0; n < 4; ++n)
        acc[m][n] = __builtin_amdgcn_mfma_f32_16x16x32_bf16(af[m], bfr[n], acc[m][n], 0, 0, 0);
  }
  #pragma unroll
  for (int m = 0; m < 4; ++m)
    #pragma unroll
    for (int n = 0; n < 4; ++n)
      #pragma unroll
      for (int r = 0; r < 4; ++r) {
        int row = bm + wr * 64 + m * 16 + fq * 4 + r;
        int col = bn + wc * 64 + n * 16 + fr;
        C[(size_t)row * N + col] = acc[m][n][r];
      }
}

// ---------------------------------- cached_kv: one thread per output element
// [VERIFIED round 4 — do not touch]
__global__ __launch_bounds__(256) void kvout_slow(
    const float* __restrict__ qkv, float* __restrict__ cached) {
  size_t gid = (size_t)blockIdx.x * 256 + threadIdx.x;  // 16,777,216
  int d = (int)(gid & 127);
  size_t r = gid >> 7;
  int n = (int)(r & 2047); r >>= 11;
  int h = (int)(r & 15);   r >>= 4;
  int b = (int)(r & 1);    r >>= 1;
  int kv = (int)r;         // 0=k, 1=v  (pre-RoPE)
  cached[gid] = qkv[(size_t)(b * SEQ + n) * NQKV + (size_t)(1 + kv) * DIM + h * DH + d];
}

// ------------------------- RoPE cos/sin table (fp64 build, fp32 store) ------
// [VERIFIED round 10 — unchanged]
__global__ __launch_bounds__(256) void rope_table(float2* __restrict__ tab) {
  int gid = blockIdx.x * 256 + threadIdx.x;   // 131072
  int p = gid & 63;
  int n = gid >> 6;
  double inv = pow(10000.0, -(double)p / 64.0);
  double ang = (double)n * inv;
  tab[gid] = make_float2((float)cos(ang), (float)sin(ang));
}

// ------------------------------------- RoPE apply in-place (fp32, per pair) -
// [VERIFIED round 10 — unchanged]
__global__ __launch_bounds__(256) void rope_apply(float* __restrict__ qkv,
                                                  const float2* __restrict__ tab) {
  int gid = blockIdx.x * 256 + threadIdx.x;   // 8,388,608 pairs (q and k)
  int p = gid & 63;
  int n = (gid >> 6) & 2047;
  int h = (gid >> 17) & 15;
  int s = (gid >> 21) & 1;    // 0 = q, 1 = k
  int b = (gid >> 22) & 1;
  float* base = qkv + (size_t)(b * SEQ + n) * NQKV + s * DIM + h * DH + 2 * p;
  float2 cs = tab[n * 64 + p];
  float2 w = *(float2*)base;
  float2 o;
  o.x = w.x * cs.x - w.y * cs.y;
  o.y = w.y * cs.x + w.x * cs.y;
  *(float2*)base = o;
}

// ------------------------- V transpose + cast -> vT[bh][d][n] (bf16) --------
// [VERIFIED round 6 — unchanged]
__global__ void transpose_v_cast(const float* __restrict__ qkv,
                                 u16* __restrict__ vT) {
  int bh = blockIdx.z; int b = bh >> 4, h = bh & 15;
  int d0 = blockIdx.x * 32, n0 = blockIdx.y * 32;
  __shared__ float tile[32][33];
  int tx = threadIdx.x, ty = threadIdx.y;   // (32,8)
  const float* src = qkv + (size_t)(b * SEQ + n0) * NQKV + 2 * DIM + h * DH + d0;
  #pragma unroll
  for (int j = 0; j < 32; j += 8)
    tile[ty + j][tx] = src[(size_t)(ty + j) * NQKV + tx];
  __syncthreads();
  u16* dst = vT + ((size_t)bh * DH + d0) * SEQ + n0;
  #pragma unroll
  for (int j = 0; j < 32; j += 8)
    dst[(size_t)(ty + j) * SEQ + tx] = f2bf(tile[tx][ty + j]);
}

// ----------------- pack post-RoPE q,k as bf16 into the dead fp32-V region ---
// [VERIFIED round 7 — unchanged]
__global__ __launch_bounds__(256) void pack_qk(float* __restrict__ qkv) {
  int row = blockIdx.x;           // 0..4095
  int t = threadIdx.x;            // 16 elems each over q+k (4096 elems)
  const float* src = qkv + (size_t)row * NQKV + t * 16;
  float4 f0 = ((const float4*)src)[0];
  float4 f1 = ((const float4*)src)[1];
  float4 f2 = ((const float4*)src)[2];
  float4 f3 = ((const float4*)src)[3];
  union { u16 h[16]; int4 q[2]; } cv;
  cv.h[0]=f2bf(f0.x);  cv.h[1]=f2bf(f0.y);  cv.h[2]=f2bf(f0.z);  cv.h[3]=f2bf(f0.w);
  cv.h[4]=f2bf(f1.x);  cv.h[5]=f2bf(f1.y);  cv.h[6]=f2bf(f1.z);  cv.h[7]=f2bf(f1.w);
  cv.h[8]=f2bf(f2.x);  cv.h[9]=f2bf(f2.y);  cv.h[10]=f2bf(f2.z); cv.h[11]=f2bf(f2.w);
  cv.h[12]=f2bf(f3.x); cv.h[13]=f2bf(f3.y); cv.h[14]=f2bf(f3.z); cv.h[15]=f2bf(f3.w);
  u16* dst = (u16*)(qkv + (size_t)row * NQKV) + 8192 + t * 16;
  ((int4*)dst)[0] = cv.q[0];
  ((int4*)dst)[1] = cv.q[1];
}

// -------- swapped-operand 32x32 MFMA causal flash attention, 1 wave ---------
// D_qk = mfma_32x32x16(A=K, B=Q) -> S^T[kv][q], col(lane&31)=q. Each lane owns
// one query's scores in 16 regs (kv = (r&3)+8*(r>>2)+4*hi per reg, hi=lane>>5)
// -> softmax is a lane-local tree + ONE shfl_xor(32). P repacked to the PV
// A-fragment in-register via bf16 pair-packing + shfl_xor(32) (T12 pattern).
// T13 defer-max (THR=8) skips acc rescale when __all(mx - m <= 8).
// C/D layout per m74/m101: col=lane&31, row=(reg&3)+8*(reg>>2)+4*(lane>>5).
// A/B input layout: row/col = lane&31, k = (lane>>5)*8 + [0..7].
// XCD-sequential bh ownership (round-11-validated decode).
__global__ __launch_bounds__(64) void attn_swap(
    const u16* __restrict__ qkp,   // u16 view of qkvf (packed q,k in V region)
    const u16* __restrict__ vT,    // (32,128,2048) bf16
    u16* __restrict__ ctx) {       // (4096, 2048) bf16
  int wg = blockIdx.x;             // 0..2047
  int xcd = wg & 7;
  int g   = wg >> 3;               // 0..255 within-XCD sequence
  int bh  = (g >> 6) * 8 + xcd;    // 0..31
  int qt  = 63 - (g & 63);         // 32-row q-tile, longest first within bh
  int b = bh >> 4, h = bh & 15;
  int lane = threadIdx.x;
  int ln = lane & 31;
  int hi = lane >> 5;
  int qr0 = qt * 32;
  int q_own = qr0 + ln;            // the query this lane's stats cover

  const size_t rstr = 2 * NQKV;    // u16 per row
  const u16* Qb = qkp + (size_t)(b * SEQ) * rstr + 8192 + h * 128;
  const u16* Kb = qkp + (size_t)(b * SEQ) * rstr + 10240 + h * 128;
  const u16* Vt = vT + (size_t)bh * DH * SEQ;

  // Q fragments (B-operand): qf[kc][e] = Q[qr0+ln][kc*16 + hi*8 + e]
  bf16x8 qf[8];
  {
    const u16* qrow = Qb + (size_t)q_own * rstr + hi * 8;
    #pragma unroll
    for (int kc = 0; kc < 8; ++kc) qf[kc] = *(const bf16x8*)(qrow + kc * 16);
  }

  f32x16 acc[4] = {};              // [db] O^T accum: col=d, rows=q
  float m = -3e38f, l = 0.f;
  const float scale = 0.08838834764831845f;

  // K fragments (A-operand), preload tile 0: K[j0+ln][kc*16 + hi*8 + e]
  bf16x8 kreg[8];
  {
    const u16* krow = Kb + (size_t)ln * rstr + hi * 8;
    #pragma unroll
    for (int kc = 0; kc < 8; ++kc) kreg[kc] = *(const bf16x8*)(krow + kc * 16);
  }

  for (int jt = 0; jt <= qt; ++jt) {
    int j0 = jt * 32;

    // V fragments for THIS tile (consumed at PV, after softmax)
    bf16x8 vfrag[8];               // [t*4+db]: V[j0+t*16+hi*8+e][db*32+ln]
    #pragma unroll
    for (int t = 0; t < 2; ++t)
      #pragma unroll
      for (int db = 0; db < 4; ++db)
        vfrag[t * 4 + db] =
            *(const bf16x8*)(Vt + (size_t)(db * 32 + ln) * SEQ + j0 + t * 16 + hi * 8);

    // QK^T (swapped): S^T[kv][q]
    f32x16 sacc = {};
    #pragma unroll
    for (int kc = 0; kc < 8; ++kc)
      sacc = __builtin_amdgcn_mfma_f32_32x32x16_bf16(kreg[kc], qf[kc], sacc, 0, 0, 0);

    // prefetch NEXT K tile (kreg dead after QK issues)
    if (jt < qt) {
      const u16* krow = Kb + (size_t)(j0 + 32 + ln) * rstr + hi * 8;
      #pragma unroll
      for (int kc = 0; kc < 8; ++kc) kreg[kc] = *(const bf16x8*)(krow + kc * 16);
    }

    // mask + scale into lane-local p[16]
    float p[16];
    #pragma unroll
    for (int r = 0; r < 16; ++r) {
      int kv = j0 + (r & 3) + 8 * (r >> 2) + 4 * hi;
      float v = sacc[r] * scale;
      p[r] = (kv > q_own) ? -1e30f : v;
    }

    // lane-local max tree + one cross-half exchange
    float t8[8];
    #pragma unroll
    for (int i = 0; i < 8; ++i) t8[i] = fmaxf(p[i], p[i + 8]);
    #pragma unroll
    for (int i = 0; i < 4; ++i) t8[i] = fmaxf(t8[i], t8[i + 4]);
    float mx = fmaxf(fmaxf(t8[0], t8[1]), fmaxf(t8[2], t8[3]));
    mx = fmaxf(mx, __shfl_xor(mx, 32));

    // T13 defer-max: rescale only when some query's max grew > 8
    if (!__all(mx - m <= 8.f)) {
      float mn = fmaxf(m, mx);
      float al = __expf(m - mn);
      m = mn;
      l *= al;
      #pragma unroll
      for (int r = 0; r < 16; ++r) {
        float alr = __shfl(al, (r & 3) + 8 * (r >> 2) + 4 * hi);
        #pragma unroll
        for (int db = 0; db < 4; ++db) acc[db][r] *= alr;
      }
    }

    // exp + lane-local sum tree + one cross-half exchange
    #pragma unroll
    for (int r = 0; r < 16; ++r) p[r] = __expf(p[r] - m);
    float s8[8];
    #pragma unroll
    for (int i = 0; i < 8; ++i) s8[i] = p[i] + p[i + 8];
    #pragma unroll
    for (int i = 0; i < 4; ++i) s8[i] = s8[i] + s8[i + 4];
    float sum = (s8[0] + s8[1]) + (s8[2] + s8[3]);
    sum += __shfl_xor(sum, 32);
    l += sum;

    // pack P to bf16 pairs, exchange halves, assemble PV A-fragments
    u32 pk[8], swk[8];
    #pragma unroll
    for (int i = 0; i < 8; ++i)
      pk[i] = (u32)f2bf(p[2 * i]) | ((u32)f2bf(p[2 * i + 1]) << 16);
    #pragma unroll
    for (int i = 0; i < 8; ++i) swk[i] = __shfl_xor(pk[i], 32);

    union { u32 w[4]; bf16x8 v; } pf0, pf1;
    pf0.w[0] = hi ? swk[2] : pk[0];
    pf0.w[1] = hi ? swk[3] : pk[1];
    pf0.w[2] = hi ? pk[2]  : swk[0];
    pf0.w[3] = hi ? pk[3]  : swk[1];
    pf1.w[0] = hi ? swk[6] : pk[4];
    pf1.w[1] = hi ? swk[7] : pk[5];
    pf1.w[2] = hi ? pk[6]  : swk[4];
    pf1.w[3] = hi ? pk[7]  : swk[5];

    // PV: O^T[q][d] += P[q][kv] * V[kv][d], two K=16 chunks x 4 d-blocks
    #pragma unroll
    for (int db = 0; db < 4; ++db) {
      acc[db] = __builtin_amdgcn_mfma_f32_32x32x16_bf16(pf0.v, vfrag[db],     acc[db], 0, 0, 0);
      acc[db] = __builtin_amdgcn_mfma_f32_32x32x16_bf16(pf1.v, vfrag[4 + db], acc[db], 0, 0, 0);
    }
  }

  // epilogue: divide by l (broadcast per output row) and store
  float linv = 1.f / l;
  #pragma unroll
  for (int r = 0; r < 16; ++r) {
    int qrow = (r & 3) + 8 * (r >> 2) + 4 * hi;
    float lr = __shfl(linv, qrow);
    int q = qr0 + qrow;
    u16* crow = ctx + (size_t)(b * SEQ + q) * DIM + h * DH + ln;
    #pragma unroll
    for (int db = 0; db < 4; ++db)
      crow[db * 32] = f2bf(acc[db][r] * lr);
  }
}

// ----------------------------------------------------------------- launch ---
extern "C" void kernel_launch(void* const* d_in, const int* in_sizes, int n_in,
                              void* d_out, int out_size, void* d_ws, size_t ws_size,
                              hipStream_t stream) {
  // size-keyed input selection (sizes are pairwise distinct)
  const float *x = nullptr, *gamma = nullptr, *wq = nullptr, *wo = nullptr;
  for (int ii = 0; ii < n_in; ++ii) {
    switch (in_sizes[ii]) {
      case  8388608: x     = (const float*)d_in[ii]; break;
      case     2048: gamma = (const float*)d_in[ii]; break;
      case 12582912: wq    = (const float*)d_in[ii]; break;
      case  4194304: wo    = (const float*)d_in[ii]; break;
    }
  }
  if (!x || !gamma || !wq || !wo) {   // fallback: documented dict order
    x = (const float*)d_in[0]; gamma = (const float*)d_in[1];
    wq = (const float*)d_in[2]; wo = (const float*)d_in[3];
  }

  float* out    = (float*)d_out;           // (2,2048,2048) = first 33.55 MB
  float* cached = out + 8388608;           // (2,2,16,2048,128) at byte 33.55M

  // ws (134.2 MB, proven footprint), time-multiplexed:
  //   [0, 25.2M)       xn(head) -> wqkvT -> ctx(first 16.8M)
  //   [25.2M, 33.55M)  xn(tail) -> woutT (live until final GEMM)
  //   [33.55M, 134.2M) qkvf (fp32; V third repurposed for packed bf16 q,k)
  // out-region scratch (dead before final GEMM writes out):
  //   out[0, 16.8M)    xnb (bf16 A) -> vT (bf16) after QKV GEMM
  //   out[16.8M,17.8M) rope table
  float* xn    = (float*)d_ws;
  u16*   wqkvT = (u16*)d_ws;
  u16*   ctx   = (u16*)d_ws;
  u16*   woutT = (u16*)((char*)d_ws + 25165824);
  float* qkvf  = (float*)((char*)d_ws + 33554432);
  u16*   xnb   = (u16*)d_out;
  u16*   vT    = (u16*)d_out;
  float2* tab  = (float2*)((char*)d_out + 16777216);

  rms_slow<<<ROWS, 64, 0, stream>>>(x, gamma, xn);
  rope_table<<<131072 / 256, 256, 0, stream>>>(tab);
  cast_bf16<<<4096, 256, 0, stream>>>(xn, xnb);                 // xn dead after
  transpose_f32_bf16<<<dim3(NQKV / 32, DIM / 32), dim3(32, 8), 0, stream>>>(wq, wqkvT, DIM, NQKV);
  transpose_f32_bf16<<<dim3(DIM / 32, DIM / 32), dim3(32, 8), 0, stream>>>(wo, woutT, DIM, DIM);
  gemm_nt<<<(ROWS / 128) * (NQKV / 128), 256, 0, stream>>>(xnb, wqkvT, qkvf, ROWS, NQKV, DIM);
  kvout_slow<<<65536, 256, 0, stream>>>(qkvf, cached);
  rope_apply<<<32768, 256, 0, stream>>>(qkvf, tab);
  transpose_v_cast<<<dim3(DH / 32, SEQ / 32, 32), dim3(32, 8), 0, stream>>>(qkvf, vT);  // overwrites dead xnb
  pack_qk<<<ROWS, 256, 0, stream>>>(qkvf);
  attn_swap<<<2048, 64, 0, stream>>>((const u16*)qkvf, vT, ctx);   // ctx overwrites dead wqkvT
  gemm_nt<<<(ROWS / 128) * (DIM / 128), 256, 0, stream>>>(ctx, woutT, out, ROWS, DIM, DIM);
}

// Round 16
// 477.779 us; speedup vs baseline: 1.2588x; 1.0761x over previous
//
#include <hip/hip_runtime.h>
#include <cstdint>
#include <cstddef>
#include <math.h>

#define SEQ   2048
#define DIM   2048
#define NQKV  6144
#define NH    16
#define DH    128
#define ROWS  4096   /* b*n */

typedef unsigned short u16;
typedef unsigned int u32;
typedef __attribute__((ext_vector_type(8))) short bf16x8;
typedef __attribute__((ext_vector_type(4))) float f32x4;
typedef __attribute__((ext_vector_type(16))) float f32x16;

__device__ __forceinline__ u16 f2bf(float f) {
  union { float f; u32 u; } v;
  v.f = f;
  u32 r = v.u + 0x7FFFu + ((v.u >> 16) & 1u);
  return (u16)(r >> 16);
}

// async global->LDS, 16B per lane; LDS dest is wave-uniform base + lane*16
__device__ __forceinline__ void gll16(const u16* g, u16* l) {
  __builtin_amdgcn_global_load_lds(
      (const __attribute__((address_space(1))) u32*)(const void*)g,
      (__attribute__((address_space(3))) u32*)(void*)l,
      16, 0, 0);
}

// ------------------------------------------------ rmsnorm (fp64, 1 wave/row)
// [VERIFIED round 4 — do not touch]
__global__ __launch_bounds__(64) void rms_slow(
    const float* __restrict__ x, const float* __restrict__ g,
    float* __restrict__ xn) {
  int row = blockIdx.x, lane = threadIdx.x;
  const float* xr = x + (size_t)row * DIM;
  double ss = 0.0;
  for (int c = lane; c < DIM; c += 64) { double v = xr[c]; ss += v * v; }
  #pragma unroll
  for (int off = 32; off >= 1; off >>= 1) ss += __shfl_xor(ss, off);
  double nrm = sqrt(ss); if (nrm < 1e-12) nrm = 1e-12;
  double sc = 45.254833995939045 / nrm;   // sqrt(2048)/||x||
  float* dst = xn + (size_t)row * DIM;
  for (int c = lane; c < DIM; c += 64) dst[c] = (float)((double)xr[c] * sc * (double)g[c]);
}

// ----------------------------------------- fp32 -> bf16 cast (8 elems/thread)
// [VERIFIED round 12 — unchanged]
__global__ __launch_bounds__(256) void cast_bf16(
    const float* __restrict__ in, u16* __restrict__ out) {
  size_t i = ((size_t)blockIdx.x * 256 + threadIdx.x) * 8;
  float4 f0 = *(const float4*)(in + i);
  float4 f1 = *(const float4*)(in + i + 4);
  union { u16 h[8]; int4 q; } cv;
  cv.h[0]=f2bf(f0.x); cv.h[1]=f2bf(f0.y); cv.h[2]=f2bf(f0.z); cv.h[3]=f2bf(f0.w);
  cv.h[4]=f2bf(f1.x); cv.h[5]=f2bf(f1.y); cv.h[6]=f2bf(f1.z); cv.h[7]=f2bf(f1.w);
  *(int4*)(out + i) = cv.q;
}

// ------------------------------------------------- fp32 -> bf16 transpose ---
// [VERIFIED round 12 — unchanged]
__global__ void transpose_f32_bf16(const float* __restrict__ in,
                                   u16* __restrict__ out, int R, int C) {
  __shared__ float tile[32][33];
  int bx = blockIdx.x * 32;   // C index
  int by = blockIdx.y * 32;   // R index
  int tx = threadIdx.x, ty = threadIdx.y;   // (32,8)
  #pragma unroll
  for (int j = 0; j < 32; j += 8)
    tile[ty + j][tx] = in[(size_t)(by + ty + j) * C + bx + tx];
  __syncthreads();
  #pragma unroll
  for (int j = 0; j < 32; j += 8)
    out[(size_t)(bx + ty + j) * R + by + tx] = f2bf(tile[tx][ty + j]);
}

// --------------- bf16 NT GEMM, XCD-swizzled, global_load_lds staging --------
// C[M,N] = A[M,K] * BT[N,K]^T, fp32 out. 128x128 tile, BK=32, 4 waves.
// m97 pattern: linear LDS [128][32] u16 (no pad — gll dest is wave-uniform
// base + lane*16), 2 gll16 pairs per wave per K-step, 2-barrier loop.
// MFMA core / fragment mapping / C-write identical to round-12-verified
// kernel (only LDS stride 40 -> 32 and staging path changed).
__global__ __launch_bounds__(256) void gemm_nt(
    const u16* __restrict__ A, const u16* __restrict__ BT,
    float* __restrict__ C, int M, int N, int K) {
  __shared__ u16 As[128 * 32];
  __shared__ u16 Bs[128 * 32];
  int nbn = N >> 7;
  int chunk = nbn >> 3;            // requires nbn % 8 == 0 (48, 16: ok)
  int wg = blockIdx.x;
  int xcd = wg & 7, g = wg >> 3;
  int bm = (g / chunk) * 128;
  int bn = (xcd * chunk + g % chunk) * 128;

  int tid = threadIdx.x;
  int wid = tid >> 6, lane = tid & 63;
  int wr = wid >> 1, wc = wid & 1;
  int fr = lane & 15, fq = lane >> 4;
  int srow_hi = lane >> 2;          // 0..15 within a 16-row chunk
  int scol = (lane & 3) * 8;        // k offset, u16 elems

  f32x4 acc[4][4] = {};

  const u16* a_rd = As + (wr * 64 + fr) * 32 + fq * 8;
  const u16* b_rd = Bs + (wc * 64 + fr) * 32 + fq * 8;

  for (int k0 = 0; k0 < K; k0 += 32) {
    __syncthreads();                // previous tile's ds_reads are retired
    #pragma unroll
    for (int i = 0; i < 2; ++i) {
      int c = wid * 2 + i;          // chunk 0..7 (16 rows x 32 k each)
      int row = c * 16 + srow_hi;
      gll16(A  + (size_t)(bm + row) * K + k0 + scol, As + c * 512);
      gll16(BT + (size_t)(bn + row) * K + k0 + scol, Bs + c * 512);
    }
    __syncthreads();                // drains vmcnt -> tiles staged

    bf16x8 af[4], bfr[4];
    #pragma unroll
    for (int m = 0; m < 4; ++m) af[m]  = *(const bf16x8*)(a_rd + m * 16 * 32);
    #pragma unroll
    for (int n = 0; n < 4; ++n) bfr[n] = *(const bf16x8*)(b_rd + n * 16 * 32);
    #pragma unroll
    for (int m = 0; m < 4; ++m)
      #pragma unroll
      for (int n = 0; n < 4; ++n)
        acc[m][n] = __builtin_amdgcn_mfma_f32_16x16x32_bf16(af[m], bfr[n], acc[m][n], 0, 0, 0);
  }
  #pragma unroll
  for (int m = 0; m < 4; ++m)
    #pragma unroll
    for (int n = 0; n < 4; ++n)
      #pragma unroll
      for (int r = 0; r < 4; ++r) {
        int row = bm + wr * 64 + m * 16 + fq * 4 + r;
        int col = bn + wc * 64 + n * 16 + fr;
        C[(size_t)row * N + col] = acc[m][n][r];
      }
}

// ------------------------- RoPE cos/sin table (fp64 build, fp32 store) ------
// [VERIFIED round 10 — unchanged]
__global__ __launch_bounds__(256) void rope_table(float2* __restrict__ tab) {
  int gid = blockIdx.x * 256 + threadIdx.x;   // 131072
  int p = gid & 63;
  int n = gid >> 6;
  double inv = pow(10000.0, -(double)p / 64.0);
  double ang = (double)n * inv;
  tab[gid] = make_float2((float)cos(ang), (float)sin(ang));
}

// ------------------------- V transpose + cast -> vT[bh][d][n] (bf16) --------
// [VERIFIED round 6 — unchanged; MUST run before kv_rope_pack (v clobber)]
__global__ void transpose_v_cast(const float* __restrict__ qkv,
                                 u16* __restrict__ vT) {
  int bh = blockIdx.z; int b = bh >> 4, h = bh & 15;
  int d0 = blockIdx.x * 32, n0 = blockIdx.y * 32;
  __shared__ float tile[32][33];
  int tx = threadIdx.x, ty = threadIdx.y;   // (32,8)
  const float* src = qkv + (size_t)(b * SEQ + n0) * NQKV + 2 * DIM + h * DH + d0;
  #pragma unroll
  for (int j = 0; j < 32; j += 8)
    tile[ty + j][tx] = src[(size_t)(ty + j) * NQKV + tx];
  __syncthreads();
  u16* dst = vT + ((size_t)bh * DH + d0) * SEQ + n0;
  #pragma unroll
  for (int j = 0; j < 32; j += 8)
    dst[(size_t)(ty + j) * SEQ + tx] = f2bf(tile[tx][ty + j]);
}

// ---- fused: cached_kv (pre-RoPE) + RoPE(q,k) + bf16 pack into v region -----
// One block per row (b,n); thread t owns cols c=t*8..t*8+7 of q, k and v.
// Formulas byte-copied from verified kvout_slow / rope_apply / pack_qk.
// The packed q,k write overwrites the fp32 v region of the same row, so all
// v loads complete before the barrier; packed writes happen after it.
__global__ __launch_bounds__(256) void kv_rope_pack(
    float* __restrict__ qkv, float* __restrict__ cached,
    const float2* __restrict__ tab) {
  int row = blockIdx.x;            // b*2048 + n
  int b = row >> 11, n = row & 2047;
  int t = threadIdx.x;
  int c = t * 8;                   // col within 2048
  int h = c >> 7, d = c & 127;
  float* base = qkv + (size_t)row * NQKV;

  float4 q0 = *(const float4*)(base + c);
  float4 q1 = *(const float4*)(base + c + 4);
  float4 k0 = *(const float4*)(base + 2048 + c);
  float4 k1 = *(const float4*)(base + 2048 + c + 4);
  float4 v0 = *(const float4*)(base + 4096 + c);
  float4 v1 = *(const float4*)(base + 4096 + c + 4);

  // cached_kv (pre-RoPE k, v) — identical addressing to kvout_slow
  size_t ob = ((size_t)(b * NH + h) * SEQ + n) * DH + d;
  *(float4*)(cached + ob)     = k0;
  *(float4*)(cached + ob + 4) = k1;
  *(float4*)(cached + 8388608 + ob)     = v0;
  *(float4*)(cached + 8388608 + ob + 4) = v1;

  // RoPE on q,k: 4 pairs per thread, table values identical to rope_apply
  int p0 = d >> 1;
  float2 cs0 = tab[n * 64 + p0];
  float2 cs1 = tab[n * 64 + p0 + 1];
  float2 cs2 = tab[n * 64 + p0 + 2];
  float2 cs3 = tab[n * 64 + p0 + 3];

  float qa0 = q0.x * cs0.x - q0.y * cs0.y, qb0 = q0.y * cs0.x + q0.x * cs0.y;
  float qa1 = q0.z * cs1.x - q0.w * cs1.y, qb1 = q0.w * cs1.x + q0.z * cs1.y;
  float qa2 = q1.x * cs2.x - q1.y * cs2.y, qb2 = q1.y * cs2.x + q1.x * cs2.y;
  float qa3 = q1.z * cs3.x - q1.w * cs3.y, qb3 = q1.w * cs3.x + q1.z * cs3.y;

  float ka0 = k0.x * cs0.x - k0.y * cs0.y, kb0 = k0.y * cs0.x + k0.x * cs0.y;
  float ka1 = k0.z * cs1.x - k0.w * cs1.y, kb1 = k0.w * cs1.x + k0.z * cs1.y;
  float ka2 = k1.x * cs2.x - k1.y * cs2.y, kb2 = k1.y * cs2.x + k1.x * cs2.y;
  float ka3 = k1.z * cs3.x - k1.w * cs3.y, kb3 = k1.w * cs3.x + k1.z * cs3.y;

  union { u16 hh[8]; int4 q; } pq, pk;
  pq.hh[0]=f2bf(qa0); pq.hh[1]=f2bf(qb0); pq.hh[2]=f2bf(qa1); pq.hh[3]=f2bf(qb1);
  pq.hh[4]=f2bf(qa2); pq.hh[5]=f2bf(qb2); pq.hh[6]=f2bf(qa3); pq.hh[7]=f2bf(qb3);
  pk.hh[0]=f2bf(ka0); pk.hh[1]=f2bf(kb0); pk.hh[2]=f2bf(ka1); pk.hh[3]=f2bf(kb1);
  pk.hh[4]=f2bf(ka2); pk.hh[5]=f2bf(kb2); pk.hh[6]=f2bf(ka3); pk.hh[7]=f2bf(kb3);

  __syncthreads();   // all v loads of this row retired before pack overwrites

  u16* ub = (u16*)base;
  *(int4*)(ub + 8192 + c)  = pq.q;   // packed q  (same slots as pack_qk)
  *(int4*)(ub + 10240 + c) = pk.q;   // packed k
}

// -------- swapped-operand 32x32 MFMA causal flash attention, 1 wave ---------
// [VERIFIED round 15 — byte-identical]
__global__ __launch_bounds__(64) void attn_swap(
    const u16* __restrict__ qkp,   // u16 view of qkvf (packed q,k in V region)
    const u16* __restrict__ vT,    // (32,128,2048) bf16
    u16* __restrict__ ctx) {       // (4096, 2048) bf16
  int wg = blockIdx.x;             // 0..2047
  int xcd = wg & 7;
  int g   = wg >> 3;               // 0..255 within-XCD sequence
  int bh  = (g >> 6) * 8 + xcd;    // 0..31
  int qt  = 63 - (g & 63);         // 32-row q-tile, longest first within bh
  int b = bh >> 4, h = bh & 15;
  int lane = threadIdx.x;
  int ln = lane & 31;
  int hi = lane >> 5;
  int qr0 = qt * 32;
  int q_own = qr0 + ln;            // the query this lane's stats cover

  const size_t rstr = 2 * NQKV;    // u16 per row
  const u16* Qb = qkp + (size_t)(b * SEQ) * rstr + 8192 + h * 128;
  const u16* Kb = qkp + (size_t)(b * SEQ) * rstr + 10240 + h * 128;
  const u16* Vt = vT + (size_t)bh * DH * SEQ;

  // Q fragments (B-operand): qf[kc][e] = Q[qr0+ln][kc*16 + hi*8 + e]
  bf16x8 qf[8];
  {
    const u16* qrow = Qb + (size_t)q_own * rstr + hi * 8;
    #pragma unroll
    for (int kc = 0; kc < 8; ++kc) qf[kc] = *(const bf16x8*)(qrow + kc * 16);
  }

  f32x16 acc[4] = {};              // [db] O^T accum: col=d, rows=q
  float m = -3e38f, l = 0.f;
  const float scale = 0.08838834764831845f;

  // K fragments (A-operand), preload tile 0: K[j0+ln][kc*16 + hi*8 + e]
  bf16x8 kreg[8];
  {
    const u16* krow = Kb + (size_t)ln * rstr + hi * 8;
    #pragma unroll
    for (int kc = 0; kc < 8; ++kc) kreg[kc] = *(const bf16x8*)(krow + kc * 16);
  }

  for (int jt = 0; jt <= qt; ++jt) {
    int j0 = jt * 32;

    // V fragments for THIS tile (consumed at PV, after softmax)
    bf16x8 vfrag[8];               // [t*4+db]: V[j0+t*16+hi*8+e][db*32+ln]
    #pragma unroll
    for (int t = 0; t < 2; ++t)
      #pragma unroll
      for (int db = 0; db < 4; ++db)
        vfrag[t * 4 + db] =
            *(const bf16x8*)(Vt + (size_t)(db * 32 + ln) * SEQ + j0 + t * 16 + hi * 8);

    // QK^T (swapped): S^T[kv][q]
    f32x16 sacc = {};
    #pragma unroll
    for (int kc = 0; kc < 8; ++kc)
      sacc = __builtin_amdgcn_mfma_f32_32x32x16_bf16(kreg[kc], qf[kc], sacc, 0, 0, 0);

    // prefetch NEXT K tile (kreg dead after QK issues)
    if (jt < qt) {
      const u16* krow = Kb + (size_t)(j0 + 32 + ln) * rstr + hi * 8;
      #pragma unroll
      for (int kc = 0; kc < 8; ++kc) kreg[kc] = *(const bf16x8*)(krow + kc * 16);
    }

    // mask + scale into lane-local p[16]
    float p[16];
    #pragma unroll
    for (int r = 0; r < 16; ++r) {
      int kv = j0 + (r & 3) + 8 * (r >> 2) + 4 * hi;
      float v = sacc[r] * scale;
      p[r] = (kv > q_own) ? -1e30f : v;
    }

    // lane-local max tree + one cross-half exchange
    float t8[8];
    #pragma unroll
    for (int i = 0; i < 8; ++i) t8[i] = fmaxf(p[i], p[i + 8]);
    #pragma unroll
    for (int i = 0; i < 4; ++i) t8[i] = fmaxf(t8[i], t8[i + 4]);
    float mx = fmaxf(fmaxf(t8[0], t8[1]), fmaxf(t8[2], t8[3]));
    mx = fmaxf(mx, __shfl_xor(mx, 32));

    // T13 defer-max: rescale only when some query's max grew > 8
    if (!__all(mx - m <= 8.f)) {
      float mn = fmaxf(m, mx);
      float al = __expf(m - mn);
      m = mn;
      l *= al;
      #pragma unroll
      for (int r = 0; r < 16; ++r) {
        float alr = __shfl(al, (r & 3) + 8 * (r >> 2) + 4 * hi);
        #pragma unroll
        for (int db = 0; db < 4; ++db) acc[db][r] *= alr;
      }
    }

    // exp + lane-local sum tree + one cross-half exchange
    #pragma unroll
    for (int r = 0; r < 16; ++r) p[r] = __expf(p[r] - m);
    float s8[8];
    #pragma unroll
    for (int i = 0; i < 8; ++i) s8[i] = p[i] + p[i + 8];
    #pragma unroll
    for (int i = 0; i < 4; ++i) s8[i] = s8[i] + s8[i + 4];
    float sum = (s8[0] + s8[1]) + (s8[2] + s8[3]);
    sum += __shfl_xor(sum, 32);
    l += sum;

    // pack P to bf16 pairs, exchange halves, assemble PV A-fragments
    u32 pk[8], swk[8];
    #pragma unroll
    for (int i = 0; i < 8; ++i)
      pk[i] = (u32)f2bf(p[2 * i]) | ((u32)f2bf(p[2 * i + 1]) << 16);
    #pragma unroll
    for (int i = 0; i < 8; ++i) swk[i] = __shfl_xor(pk[i], 32);

    union { u32 w[4]; bf16x8 v; } pf0, pf1;
    pf0.w[0] = hi ? swk[2] : pk[0];
    pf0.w[1] = hi ? swk[3] : pk[1];
    pf0.w[2] = hi ? pk[2]  : swk[0];
    pf0.w[3] = hi ? pk[3]  : swk[1];
    pf1.w[0] = hi ? swk[6] : pk[4];
    pf1.w[1] = hi ? swk[7] : pk[5];
    pf1.w[2] = hi ? pk[6]  : swk[4];
    pf1.w[3] = hi ? pk[7]  : swk[5];

    // PV: O^T[q][d] += P[q][kv] * V[kv][d], two K=16 chunks x 4 d-blocks
    #pragma unroll
    for (int db = 0; db < 4; ++db) {
      acc[db] = __builtin_amdgcn_mfma_f32_32x32x16_bf16(pf0.v, vfrag[db],     acc[db], 0, 0, 0);
      acc[db] = __builtin_amdgcn_mfma_f32_32x32x16_bf16(pf1.v, vfrag[4 + db], acc[db], 0, 0, 0);
    }
  }

  // epilogue: divide by l (broadcast per output row) and store
  float linv = 1.f / l;
  #pragma unroll
  for (int r = 0; r < 16; ++r) {
    int qrow = (r & 3) + 8 * (r >> 2) + 4 * hi;
    float lr = __shfl(linv, qrow);
    int q = qr0 + qrow;
    u16* crow = ctx + (size_t)(b * SEQ + q) * DIM + h * DH + ln;
    #pragma unroll
    for (int db = 0; db < 4; ++db)
      crow[db * 32] = f2bf(acc[db][r] * lr);
  }
}

// ----------------------------------------------------------------- launch ---
extern "C" void kernel_launch(void* const* d_in, const int* in_sizes, int n_in,
                              void* d_out, int out_size, void* d_ws, size_t ws_size,
                              hipStream_t stream) {
  // size-keyed input selection (sizes are pairwise distinct)
  const float *x = nullptr, *gamma = nullptr, *wq = nullptr, *wo = nullptr;
  for (int ii = 0; ii < n_in; ++ii) {
    switch (in_sizes[ii]) {
      case  8388608: x     = (const float*)d_in[ii]; break;
      case     2048: gamma = (const float*)d_in[ii]; break;
      case 12582912: wq    = (const float*)d_in[ii]; break;
      case  4194304: wo    = (const float*)d_in[ii]; break;
    }
  }
  if (!x || !gamma || !wq || !wo) {   // fallback: documented dict order
    x = (const float*)d_in[0]; gamma = (const float*)d_in[1];
    wq = (const float*)d_in[2]; wo = (const float*)d_in[3];
  }

  float* out    = (float*)d_out;           // (2,2048,2048) = first 33.55 MB
  float* cached = out + 8388608;           // (2,2,16,2048,128) at byte 33.55M

  // ws (134.2 MB, proven footprint), time-multiplexed:
  //   [0, 25.2M)       xn(head) -> wqkvT -> ctx(first 16.8M)
  //   [25.2M, 33.55M)  xn(tail) -> woutT (live until final GEMM)
  //   [33.55M, 134.2M) qkvf (fp32; V third repurposed for packed bf16 q,k)
  // out-region scratch (dead before final GEMM writes out):
  //   out[0, 16.8M)    xnb (bf16 A) -> vT (bf16) after QKV GEMM
  //   out[16.8M,17.8M) rope table
  float* xn    = (float*)d_ws;
  u16*   wqkvT = (u16*)d_ws;
  u16*   ctx   = (u16*)d_ws;
  u16*   woutT = (u16*)((char*)d_ws + 25165824);
  float* qkvf  = (float*)((char*)d_ws + 33554432);
  u16*   xnb   = (u16*)d_out;
  u16*   vT    = (u16*)d_out;
  float2* tab  = (float2*)((char*)d_out + 16777216);

  rms_slow<<<ROWS, 64, 0, stream>>>(x, gamma, xn);
  rope_table<<<131072 / 256, 256, 0, stream>>>(tab);
  cast_bf16<<<4096, 256, 0, stream>>>(xn, xnb);                 // xn dead after
  transpose_f32_bf16<<<dim3(NQKV / 32, DIM / 32), dim3(32, 8), 0, stream>>>(wq, wqkvT, DIM, NQKV);
  transpose_f32_bf16<<<dim3(DIM / 32, DIM / 32), dim3(32, 8), 0, stream>>>(wo, woutT, DIM, DIM);
  gemm_nt<<<(ROWS / 128) * (NQKV / 128), 256, 0, stream>>>(xnb, wqkvT, qkvf, ROWS, NQKV, DIM);
  transpose_v_cast<<<dim3(DH / 32, SEQ / 32, 32), dim3(32, 8), 0, stream>>>(qkvf, vT);  // overwrites dead xnb
  kv_rope_pack<<<ROWS, 256, 0, stream>>>(qkvf, cached, tab);    // after transpose_v (v clobber)
  attn_swap<<<2048, 64, 0, stream>>>((const u16*)qkvf, vT, ctx);   // ctx overwrites dead wqkvT
  gemm_nt<<<(ROWS / 128) * (DIM / 128), 256, 0, stream>>>(ctx, woutT, out, ROWS, DIM, DIM);
}

// Round 17
// 425.439 us; speedup vs baseline: 1.4136x; 1.1230x over previous
//
#include <hip/hip_runtime.h>
#include <cstdint>
#include <cstddef>
#include <math.h>

#define SEQ   2048
#define DIM   2048
#define NQKV  6144
#define NH    16
#define DH    128
#define ROWS  4096   /* b*n */

typedef unsigned short u16;
typedef unsigned int u32;
typedef __attribute__((ext_vector_type(8))) short bf16x8;
typedef __attribute__((ext_vector_type(4))) float f32x4;
typedef __attribute__((ext_vector_type(16))) float f32x16;

__device__ __forceinline__ u16 f2bf(float f) {
  union { float f; u32 u; } v;
  v.f = f;
  u32 r = v.u + 0x7FFFu + ((v.u >> 16) & 1u);
  return (u16)(r >> 16);
}

// async global->LDS, 16B per lane; LDS dest is wave-uniform base + lane*16
__device__ __forceinline__ void gll16(const u16* g, u16* l) {
  __builtin_amdgcn_global_load_lds(
      (const __attribute__((address_space(1))) u32*)(const void*)g,
      (__attribute__((address_space(3))) u32*)(void*)l,
      16, 0, 0);
}

// ------------------------------------------------ rmsnorm (fp64, 1 wave/row)
// [VERIFIED round 4 — do not touch]
__global__ __launch_bounds__(64) void rms_slow(
    const float* __restrict__ x, const float* __restrict__ g,
    float* __restrict__ xn) {
  int row = blockIdx.x, lane = threadIdx.x;
  const float* xr = x + (size_t)row * DIM;
  double ss = 0.0;
  for (int c = lane; c < DIM; c += 64) { double v = xr[c]; ss += v * v; }
  #pragma unroll
  for (int off = 32; off >= 1; off >>= 1) ss += __shfl_xor(ss, off);
  double nrm = sqrt(ss); if (nrm < 1e-12) nrm = 1e-12;
  double sc = 45.254833995939045 / nrm;   // sqrt(2048)/||x||
  float* dst = xn + (size_t)row * DIM;
  for (int c = lane; c < DIM; c += 64) dst[c] = (float)((double)xr[c] * sc * (double)g[c]);
}

// ----------------------------------------- fp32 -> bf16 cast (8 elems/thread)
// [VERIFIED round 12 — unchanged]
__global__ __launch_bounds__(256) void cast_bf16(
    const float* __restrict__ in, u16* __restrict__ out) {
  size_t i = ((size_t)blockIdx.x * 256 + threadIdx.x) * 8;
  float4 f0 = *(const float4*)(in + i);
  float4 f1 = *(const float4*)(in + i + 4);
  union { u16 h[8]; int4 q; } cv;
  cv.h[0]=f2bf(f0.x); cv.h[1]=f2bf(f0.y); cv.h[2]=f2bf(f0.z); cv.h[3]=f2bf(f0.w);
  cv.h[4]=f2bf(f1.x); cv.h[5]=f2bf(f1.y); cv.h[6]=f2bf(f1.z); cv.h[7]=f2bf(f1.w);
  *(int4*)(out + i) = cv.q;
}

// ------------------------------------------------- fp32 -> bf16 transpose ---
// [VERIFIED round 12 — unchanged]
__global__ void transpose_f32_bf16(const float* __restrict__ in,
                                   u16* __restrict__ out, int R, int C) {
  __shared__ float tile[32][33];
  int bx = blockIdx.x * 32;   // C index
  int by = blockIdx.y * 32;   // R index
  int tx = threadIdx.x, ty = threadIdx.y;   // (32,8)
  #pragma unroll
  for (int j = 0; j < 32; j += 8)
    tile[ty + j][tx] = in[(size_t)(by + ty + j) * C + bx + tx];
  __syncthreads();
  #pragma unroll
  for (int j = 0; j < 32; j += 8)
    out[(size_t)(bx + ty + j) * R + by + tx] = f2bf(tile[tx][ty + j]);
}

// --------------- bf16 NT GEMM, XCD-swizzled, global_load_lds staging --------
// [VERIFIED round 16 — unchanged]
__global__ __launch_bounds__(256) void gemm_nt(
    const u16* __restrict__ A, const u16* __restrict__ BT,
    float* __restrict__ C, int M, int N, int K) {
  __shared__ u16 As[128 * 32];
  __shared__ u16 Bs[128 * 32];
  int nbn = N >> 7;
  int chunk = nbn >> 3;            // requires nbn % 8 == 0 (48, 16: ok)
  int wg = blockIdx.x;
  int xcd = wg & 7, g = wg >> 3;
  int bm = (g / chunk) * 128;
  int bn = (xcd * chunk + g % chunk) * 128;

  int tid = threadIdx.x;
  int wid = tid >> 6, lane = tid & 63;
  int wr = wid >> 1, wc = wid & 1;
  int fr = lane & 15, fq = lane >> 4;
  int srow_hi = lane >> 2;          // 0..15 within a 16-row chunk
  int scol = (lane & 3) * 8;        // k offset, u16 elems

  f32x4 acc[4][4] = {};

  const u16* a_rd = As + (wr * 64 + fr) * 32 + fq * 8;
  const u16* b_rd = Bs + (wc * 64 + fr) * 32 + fq * 8;

  for (int k0 = 0; k0 < K; k0 += 32) {
    __syncthreads();                // previous tile's ds_reads are retired
    #pragma unroll
    for (int i = 0; i < 2; ++i) {
      int c = wid * 2 + i;          // chunk 0..7 (16 rows x 32 k each)
      int row = c * 16 + srow_hi;
      gll16(A  + (size_t)(bm + row) * K + k0 + scol, As + c * 512);
      gll16(BT + (size_t)(bn + row) * K + k0 + scol, Bs + c * 512);
    }
    __syncthreads();                // drains vmcnt -> tiles staged

    bf16x8 af[4], bfr[4];
    #pragma unroll
    for (int m = 0; m < 4; ++m) af[m]  = *(const bf16x8*)(a_rd + m * 16 * 32);
    #pragma unroll
    for (int n = 0; n < 4; ++n) bfr[n] = *(const bf16x8*)(b_rd + n * 16 * 32);
    #pragma unroll
    for (int m = 0; m < 4; ++m)
      #pragma unroll
      for (int n = 0; n < 4; ++n)
        acc[m][n] = __builtin_amdgcn_mfma_f32_16x16x32_bf16(af[m], bfr[n], acc[m][n], 0, 0, 0);
  }
  #pragma unroll
  for (int m = 0; m < 4; ++m)
    #pragma unroll
    for (int n = 0; n < 4; ++n)
      #pragma unroll
      for (int r = 0; r < 4; ++r) {
        int row = bm + wr * 64 + m * 16 + fq * 4 + r;
        int col = bn + wc * 64 + n * 16 + fr;
        C[(size_t)row * N + col] = acc[m][n][r];
      }
}

// ------------------------- RoPE cos/sin table (fp64 build, fp32 store) ------
// [VERIFIED round 10 — unchanged]
__global__ __launch_bounds__(256) void rope_table(float2* __restrict__ tab) {
  int gid = blockIdx.x * 256 + threadIdx.x;   // 131072
  int p = gid & 63;
  int n = gid >> 6;
  double inv = pow(10000.0, -(double)p / 64.0);
  double ang = (double)n * inv;
  tab[gid] = make_float2((float)cos(ang), (float)sin(ang));
}

// ------------------------- V transpose + cast -> vT[bh][d][n] (bf16) --------
// [VERIFIED round 6 — unchanged; MUST run before kv_rope_pack (v clobber)]
__global__ void transpose_v_cast(const float* __restrict__ qkv,
                                 u16* __restrict__ vT) {
  int bh = blockIdx.z; int b = bh >> 4, h = bh & 15;
  int d0 = blockIdx.x * 32, n0 = blockIdx.y * 32;
  __shared__ float tile[32][33];
  int tx = threadIdx.x, ty = threadIdx.y;   // (32,8)
  const float* src = qkv + (size_t)(b * SEQ + n0) * NQKV + 2 * DIM + h * DH + d0;
  #pragma unroll
  for (int j = 0; j < 32; j += 8)
    tile[ty + j][tx] = src[(size_t)(ty + j) * NQKV + tx];
  __syncthreads();
  u16* dst = vT + ((size_t)bh * DH + d0) * SEQ + n0;
  #pragma unroll
  for (int j = 0; j < 32; j += 8)
    dst[(size_t)(ty + j) * SEQ + tx] = f2bf(tile[tx][ty + j]);
}

// ---- fused: cached_kv (pre-RoPE) + RoPE(q,k) + bf16 pack into v region -----
// [VERIFIED round 16 — unchanged]
__global__ __launch_bounds__(256) void kv_rope_pack(
    float* __restrict__ qkv, float* __restrict__ cached,
    const float2* __restrict__ tab) {
  int row = blockIdx.x;            // b*2048 + n
  int b = row >> 11, n = row & 2047;
  int t = threadIdx.x;
  int c = t * 8;                   // col within 2048
  int h = c >> 7, d = c & 127;
  float* base = qkv + (size_t)row * NQKV;

  float4 q0 = *(const float4*)(base + c);
  float4 q1 = *(const float4*)(base + c + 4);
  float4 k0 = *(const float4*)(base + 2048 + c);
  float4 k1 = *(const float4*)(base + 2048 + c + 4);
  float4 v0 = *(const float4*)(base + 4096 + c);
  float4 v1 = *(const float4*)(base + 4096 + c + 4);

  size_t ob = ((size_t)(b * NH + h) * SEQ + n) * DH + d;
  *(float4*)(cached + ob)     = k0;
  *(float4*)(cached + ob + 4) = k1;
  *(float4*)(cached + 8388608 + ob)     = v0;
  *(float4*)(cached + 8388608 + ob + 4) = v1;

  int p0 = d >> 1;
  float2 cs0 = tab[n * 64 + p0];
  float2 cs1 = tab[n * 64 + p0 + 1];
  float2 cs2 = tab[n * 64 + p0 + 2];
  float2 cs3 = tab[n * 64 + p0 + 3];

  float qa0 = q0.x * cs0.x - q0.y * cs0.y, qb0 = q0.y * cs0.x + q0.x * cs0.y;
  float qa1 = q0.z * cs1.x - q0.w * cs1.y, qb1 = q0.w * cs1.x + q0.z * cs1.y;
  float qa2 = q1.x * cs2.x - q1.y * cs2.y, qb2 = q1.y * cs2.x + q1.x * cs2.y;
  float qa3 = q1.z * cs3.x - q1.w * cs3.y, qb3 = q1.w * cs3.x + q1.z * cs3.y;

  float ka0 = k0.x * cs0.x - k0.y * cs0.y, kb0 = k0.y * cs0.x + k0.x * cs0.y;
  float ka1 = k0.z * cs1.x - k0.w * cs1.y, kb1 = k0.w * cs1.x + k0.z * cs1.y;
  float ka2 = k1.x * cs2.x - k1.y * cs2.y, kb2 = k1.y * cs2.x + k1.x * cs2.y;
  float ka3 = k1.z * cs3.x - k1.w * cs3.y, kb3 = k1.w * cs3.x + k1.z * cs3.y;

  union { u16 hh[8]; int4 q; } pq, pk;
  pq.hh[0]=f2bf(qa0); pq.hh[1]=f2bf(qb0); pq.hh[2]=f2bf(qa1); pq.hh[3]=f2bf(qb1);
  pq.hh[4]=f2bf(qa2); pq.hh[5]=f2bf(qb2); pq.hh[6]=f2bf(qa3); pq.hh[7]=f2bf(qb3);
  pk.hh[0]=f2bf(ka0); pk.hh[1]=f2bf(kb0); pk.hh[2]=f2bf(ka1); pk.hh[3]=f2bf(kb1);
  pk.hh[4]=f2bf(ka2); pk.hh[5]=f2bf(kb2); pk.hh[6]=f2bf(ka3); pk.hh[7]=f2bf(kb3);

  __syncthreads();   // all v loads of this row retired before pack overwrites

  u16* ub = (u16*)base;
  *(int4*)(ub + 8192 + c)  = pq.q;   // packed q  (same slots as pack_qk)
  *(int4*)(ub + 10240 + c) = pk.q;   // packed k
}

// -------- swapped-operand 32x32 MFMA causal flash attention, 1 wave ---------
// Round-15-verified tile body with three changes:
//  (1) causal load balancing: each wave processes q-tiles (qt, 63-qt) of ONE
//      bh sequentially -> every wave runs exactly 65 KV-tile iterations
//      (round-16 diagnosis: makespan was set by the 64-iter tail blocks
//      running nearly alone; uniform waves keep 4 waves/CU for the whole
//      kernel). Grid 1024, XCD-ownership decode preserved.
//  (2) QK accumulator split into two independent 4-chains + VALU merge
//      (halves the dependent-MFMA chain).
//  (3) s_setprio(1) around MFMA clusters (T5; +4-7% on independent-wave
//      attention per m191).
__global__ __launch_bounds__(64) void attn_swap(
    const u16* __restrict__ qkp,   // u16 view of qkvf (packed q,k in V region)
    const u16* __restrict__ vT,    // (32,128,2048) bf16
    u16* __restrict__ ctx) {       // (4096, 2048) bf16
  int wg = blockIdx.x;             // 0..1023
  int xcd = wg & 7;
  int g   = wg >> 3;               // 0..127 within-XCD sequence
  int bh  = (g >> 5) * 8 + xcd;    // 0..31 (XCD x owns bh = x,8+x,16+x,24+x)
  int qp  = g & 31;                // pair index
  int b = bh >> 4, h = bh & 15;
  int lane = threadIdx.x;
  int ln = lane & 31;
  int hi = lane >> 5;

  const size_t rstr = 2 * NQKV;    // u16 per row
  const u16* Qb = qkp + (size_t)(b * SEQ) * rstr + 8192 + h * 128;
  const u16* Kb = qkp + (size_t)(b * SEQ) * rstr + 10240 + h * 128;
  const u16* Vt = vT + (size_t)bh * DH * SEQ;
  const float scale = 0.08838834764831845f;

  #pragma unroll 1
  for (int ph = 0; ph < 2; ++ph) {
    int qt = ph ? (63 - qp) : qp;  // (qt+1)+(64-qt) = 65 iters per wave
    int qr0 = qt * 32;
    int q_own = qr0 + ln;          // the query this lane's stats cover

    // Q fragments (B-operand): qf[kc][e] = Q[qr0+ln][kc*16 + hi*8 + e]
    bf16x8 qf[8];
    {
      const u16* qrow = Qb + (size_t)q_own * rstr + hi * 8;
      #pragma unroll
      for (int kc = 0; kc < 8; ++kc) qf[kc] = *(const bf16x8*)(qrow + kc * 16);
    }

    f32x16 acc[4] = {};            // [db] O^T accum: col=d, rows=q
    float m = -3e38f, l = 0.f;

    // K fragments (A-operand), preload tile 0: K[j0+ln][kc*16 + hi*8 + e]
    bf16x8 kreg[8];
    {
      const u16* krow = Kb + (size_t)ln * rstr + hi * 8;
      #pragma unroll
      for (int kc = 0; kc < 8; ++kc) kreg[kc] = *(const bf16x8*)(krow + kc * 16);
    }

    for (int jt = 0; jt <= qt; ++jt) {
      int j0 = jt * 32;

      // V fragments for THIS tile (consumed at PV, after softmax)
      bf16x8 vfrag[8];             // [t*4+db]: V[j0+t*16+hi*8+e][db*32+ln]
      #pragma unroll
      for (int t = 0; t < 2; ++t)
        #pragma unroll
        for (int db = 0; db < 4; ++db)
          vfrag[t * 4 + db] =
              *(const bf16x8*)(Vt + (size_t)(db * 32 + ln) * SEQ + j0 + t * 16 + hi * 8);

      // QK^T (swapped): S^T[kv][q] — two independent 4-chains, then merge
      f32x16 sacc0 = {}, sacc1 = {};
      __builtin_amdgcn_s_setprio(1);
      #pragma unroll
      for (int kc = 0; kc < 4; ++kc)
        sacc0 = __builtin_amdgcn_mfma_f32_32x32x16_bf16(kreg[kc], qf[kc], sacc0, 0, 0, 0);
      #pragma unroll
      for (int kc = 4; kc < 8; ++kc)
        sacc1 = __builtin_amdgcn_mfma_f32_32x32x16_bf16(kreg[kc], qf[kc], sacc1, 0, 0, 0);
      __builtin_amdgcn_s_setprio(0);
      f32x16 sacc = sacc0 + sacc1;

      // prefetch NEXT K tile (kreg dead after QK issues)
      if (jt < qt) {
        const u16* krow = Kb + (size_t)(j0 + 32 + ln) * rstr + hi * 8;
        #pragma unroll
        for (int kc = 0; kc < 8; ++kc) kreg[kc] = *(const bf16x8*)(krow + kc * 16);
      }

      // mask + scale into lane-local p[16]
      float p[16];
      #pragma unroll
      for (int r = 0; r < 16; ++r) {
        int kv = j0 + (r & 3) + 8 * (r >> 2) + 4 * hi;
        float v = sacc[r] * scale;
        p[r] = (kv > q_own) ? -1e30f : v;
      }

      // lane-local max tree + one cross-half exchange
      float t8[8];
      #pragma unroll
      for (int i = 0; i < 8; ++i) t8[i] = fmaxf(p[i], p[i + 8]);
      #pragma unroll
      for (int i = 0; i < 4; ++i) t8[i] = fmaxf(t8[i], t8[i + 4]);
      float mx = fmaxf(fmaxf(t8[0], t8[1]), fmaxf(t8[2], t8[3]));
      mx = fmaxf(mx, __shfl_xor(mx, 32));

      // T13 defer-max: rescale only when some query's max grew > 8
      if (!__all(mx - m <= 8.f)) {
        float mn = fmaxf(m, mx);
        float al = __expf(m - mn);
        m = mn;
        l *= al;
        #pragma unroll
        for (int r = 0; r < 16; ++r) {
          float alr = __shfl(al, (r & 3) + 8 * (r >> 2) + 4 * hi);
          #pragma unroll
          for (int db = 0; db < 4; ++db) acc[db][r] *= alr;
        }
      }

      // exp + lane-local sum tree + one cross-half exchange
      #pragma unroll
      for (int r = 0; r < 16; ++r) p[r] = __expf(p[r] - m);
      float s8[8];
      #pragma unroll
      for (int i = 0; i < 8; ++i) s8[i] = p[i] + p[i + 8];
      #pragma unroll
      for (int i = 0; i < 4; ++i) s8[i] = s8[i] + s8[i + 4];
      float sum = (s8[0] + s8[1]) + (s8[2] + s8[3]);
      sum += __shfl_xor(sum, 32);
      l += sum;

      // pack P to bf16 pairs, exchange halves, assemble PV A-fragments
      u32 pk[8], swk[8];
      #pragma unroll
      for (int i = 0; i < 8; ++i)
        pk[i] = (u32)f2bf(p[2 * i]) | ((u32)f2bf(p[2 * i + 1]) << 16);
      #pragma unroll
      for (int i = 0; i < 8; ++i) swk[i] = __shfl_xor(pk[i], 32);

      union { u32 w[4]; bf16x8 v; } pf0, pf1;
      pf0.w[0] = hi ? swk[2] : pk[0];
      pf0.w[1] = hi ? swk[3] : pk[1];
      pf0.w[2] = hi ? pk[2]  : swk[0];
      pf0.w[3] = hi ? pk[3]  : swk[1];
      pf1.w[0] = hi ? swk[6] : pk[4];
      pf1.w[1] = hi ? swk[7] : pk[5];
      pf1.w[2] = hi ? pk[6]  : swk[4];
      pf1.w[3] = hi ? pk[7]  : swk[5];

      // PV: O^T[q][d] += P[q][kv] * V[kv][d], two K=16 chunks x 4 d-blocks
      __builtin_amdgcn_s_setprio(1);
      #pragma unroll
      for (int db = 0; db < 4; ++db) {
        acc[db] = __builtin_amdgcn_mfma_f32_32x32x16_bf16(pf0.v, vfrag[db],     acc[db], 0, 0, 0);
        acc[db] = __builtin_amdgcn_mfma_f32_32x32x16_bf16(pf1.v, vfrag[4 + db], acc[db], 0, 0, 0);
      }
      __builtin_amdgcn_s_setprio(0);
    }

    // epilogue: divide by l (broadcast per output row) and store
    float linv = 1.f / l;
    #pragma unroll
    for (int r = 0; r < 16; ++r) {
      int qrow = (r & 3) + 8 * (r >> 2) + 4 * hi;
      float lr = __shfl(linv, qrow);
      int q = qr0 + qrow;
      u16* crow = ctx + (size_t)(b * SEQ + q) * DIM + h * DH + ln;
      #pragma unroll
      for (int db = 0; db < 4; ++db)
        crow[db * 32] = f2bf(acc[db][r] * lr);
    }
  }
}

// ----------------------------------------------------------------- launch ---
extern "C" void kernel_launch(void* const* d_in, const int* in_sizes, int n_in,
                              void* d_out, int out_size, void* d_ws, size_t ws_size,
                              hipStream_t stream) {
  // size-keyed input selection (sizes are pairwise distinct)
  const float *x = nullptr, *gamma = nullptr, *wq = nullptr, *wo = nullptr;
  for (int ii = 0; ii < n_in; ++ii) {
    switch (in_sizes[ii]) {
      case  8388608: x     = (const float*)d_in[ii]; break;
      case     2048: gamma = (const float*)d_in[ii]; break;
      case 12582912: wq    = (const float*)d_in[ii]; break;
      case  4194304: wo    = (const float*)d_in[ii]; break;
    }
  }
  if (!x || !gamma || !wq || !wo) {   // fallback: documented dict order
    x = (const float*)d_in[0]; gamma = (const float*)d_in[1];
    wq = (const float*)d_in[2]; wo = (const float*)d_in[3];
  }

  float* out    = (float*)d_out;           // (2,2048,2048) = first 33.55 MB
  float* cached = out + 8388608;           // (2,2,16,2048,128) at byte 33.55M

  // ws (134.2 MB, proven footprint), time-multiplexed:
  //   [0, 25.2M)       xn(head) -> wqkvT -> ctx(first 16.8M)
  //   [25.2M, 33.55M)  xn(tail) -> woutT (live until final GEMM)
  //   [33.55M, 134.2M) qkvf (fp32; V third repurposed for packed bf16 q,k)
  // out-region scratch (dead before final GEMM writes out):
  //   out[0, 16.8M)    xnb (bf16 A) -> vT (bf16) after QKV GEMM
  //   out[16.8M,17.8M) rope table
  float* xn    = (float*)d_ws;
  u16*   wqkvT = (u16*)d_ws;
  u16*   ctx   = (u16*)d_ws;
  u16*   woutT = (u16*)((char*)d_ws + 25165824);
  float* qkvf  = (float*)((char*)d_ws + 33554432);
  u16*   xnb   = (u16*)d_out;
  u16*   vT    = (u16*)d_out;
  float2* tab  = (float2*)((char*)d_out + 16777216);

  rms_slow<<<ROWS, 64, 0, stream>>>(x, gamma, xn);
  rope_table<<<131072 / 256, 256, 0, stream>>>(tab);
  cast_bf16<<<4096, 256, 0, stream>>>(xn, xnb);                 // xn dead after
  transpose_f32_bf16<<<dim3(NQKV / 32, DIM / 32), dim3(32, 8), 0, stream>>>(wq, wqkvT, DIM, NQKV);
  transpose_f32_bf16<<<dim3(DIM / 32, DIM / 32), dim3(32, 8), 0, stream>>>(wo, woutT, DIM, DIM);
  gemm_nt<<<(ROWS / 128) * (NQKV / 128), 256, 0, stream>>>(xnb, wqkvT, qkvf, ROWS, NQKV, DIM);
  transpose_v_cast<<<dim3(DH / 32, SEQ / 32, 32), dim3(32, 8), 0, stream>>>(qkvf, vT);  // overwrites dead xnb
  kv_rope_pack<<<ROWS, 256, 0, stream>>>(qkvf, cached, tab);    // after transpose_v (v clobber)
  attn_swap<<<1024, 64, 0, stream>>>((const u16*)qkvf, vT, ctx);   // ctx overwrites dead wqkvT
  gemm_nt<<<(ROWS / 128) * (DIM / 128), 256, 0, stream>>>(ctx, woutT, out, ROWS, DIM, DIM);
}

// Round 18
// 414.121 us; speedup vs baseline: 1.4523x; 1.0273x over previous
//
#include <hip/hip_runtime.h>
#include <cstdint>
#include <cstddef>
#include <math.h>

#define SEQ   2048
#define DIM   2048
#define NQKV  6144
#define NH    16
#define DH    128
#define ROWS  4096   /* b*n */

typedef unsigned short u16;
typedef unsigned int u32;
typedef __attribute__((ext_vector_type(8))) short bf16x8;
typedef __attribute__((ext_vector_type(4))) float f32x4;
typedef __attribute__((ext_vector_type(16))) float f32x16;

__device__ __forceinline__ u16 f2bf(float f) {
  union { float f; u32 u; } v;
  v.f = f;
  u32 r = v.u + 0x7FFFu + ((v.u >> 16) & 1u);
  return (u16)(r >> 16);
}

// async global->LDS, 16B per lane; LDS dest is wave-uniform base + lane*16
__device__ __forceinline__ void gll16(const u16* g, u16* l) {
  __builtin_amdgcn_global_load_lds(
      (const __attribute__((address_space(1))) u32*)(const void*)g,
      (__attribute__((address_space(3))) u32*)(void*)l,
      16, 0, 0);
}

// --------------------- rmsnorm + bf16 cast fused (fp64 core = round-4) -----
// Identical math to verified rms_slow; the fp32 value that used to be stored
// and re-read by cast_bf16 is f2bf'd directly (bit-identical output).
__global__ __launch_bounds__(64) void rms_bf16(
    const float* __restrict__ x, const float* __restrict__ g,
    u16* __restrict__ xnb) {
  int row = blockIdx.x, lane = threadIdx.x;
  const float* xr = x + (size_t)row * DIM;
  double ss = 0.0;
  for (int c = lane; c < DIM; c += 64) { double v = xr[c]; ss += v * v; }
  #pragma unroll
  for (int off = 32; off >= 1; off >>= 1) ss += __shfl_xor(ss, off);
  double nrm = sqrt(ss); if (nrm < 1e-12) nrm = 1e-12;
  double sc = 45.254833995939045 / nrm;   // sqrt(2048)/||x||
  u16* dst = xnb + (size_t)row * DIM;
  for (int c = lane; c < DIM; c += 64)
    dst[c] = f2bf((float)((double)xr[c] * sc * (double)g[c]));
}

// ------------------------------------------------- fp32 -> bf16 transpose ---
// [VERIFIED round 12 — unchanged]
__global__ void transpose_f32_bf16(const float* __restrict__ in,
                                   u16* __restrict__ out, int R, int C) {
  __shared__ float tile[32][33];
  int bx = blockIdx.x * 32;   // C index
  int by = blockIdx.y * 32;   // R index
  int tx = threadIdx.x, ty = threadIdx.y;   // (32,8)
  #pragma unroll
  for (int j = 0; j < 32; j += 8)
    tile[ty + j][tx] = in[(size_t)(by + ty + j) * C + bx + tx];
  __syncthreads();
  #pragma unroll
  for (int j = 0; j < 32; j += 8)
    out[(size_t)(bx + ty + j) * R + by + tx] = f2bf(tile[tx][ty + j]);
}

// ------------------------- RoPE cos/sin table (fp64 build, fp32 store) ------
// [VERIFIED round 10 — unchanged]
__global__ __launch_bounds__(256) void rope_table(float2* __restrict__ tab) {
  int gid = blockIdx.x * 256 + threadIdx.x;   // 131072
  int p = gid & 63;
  int n = gid >> 6;
  double inv = pow(10000.0, -(double)p / 64.0);
  double ang = (double)n * inv;
  tab[gid] = make_float2((float)cos(ang), (float)sin(ang));
}

// --------------- bf16 NT GEMM, XCD-swizzled, global_load_lds staging --------
// [VERIFIED round 16 — unchanged; used for the output projection]
__global__ __launch_bounds__(256) void gemm_nt(
    const u16* __restrict__ A, const u16* __restrict__ BT,
    float* __restrict__ C, int M, int N, int K) {
  __shared__ u16 As[128 * 32];
  __shared__ u16 Bs[128 * 32];
  int nbn = N >> 7;
  int chunk = nbn >> 3;            // requires nbn % 8 == 0
  int wg = blockIdx.x;
  int xcd = wg & 7, g = wg >> 3;
  int bm = (g / chunk) * 128;
  int bn = (xcd * chunk + g % chunk) * 128;

  int tid = threadIdx.x;
  int wid = tid >> 6, lane = tid & 63;
  int wr = wid >> 1, wc = wid & 1;
  int fr = lane & 15, fq = lane >> 4;
  int srow_hi = lane >> 2;
  int scol = (lane & 3) * 8;

  f32x4 acc[4][4] = {};

  const u16* a_rd = As + (wr * 64 + fr) * 32 + fq * 8;
  const u16* b_rd = Bs + (wc * 64 + fr) * 32 + fq * 8;

  for (int k0 = 0; k0 < K; k0 += 32) {
    __syncthreads();
    #pragma unroll
    for (int i = 0; i < 2; ++i) {
      int c = wid * 2 + i;
      int row = c * 16 + srow_hi;
      gll16(A  + (size_t)(bm + row) * K + k0 + scol, As + c * 512);
      gll16(BT + (size_t)(bn + row) * K + k0 + scol, Bs + c * 512);
    }
    __syncthreads();

    bf16x8 af[4], bfr[4];
    #pragma unroll
    for (int m = 0; m < 4; ++m) af[m]  = *(const bf16x8*)(a_rd + m * 16 * 32);
    #pragma unroll
    for (int n = 0; n < 4; ++n) bfr[n] = *(const bf16x8*)(b_rd + n * 16 * 32);
    #pragma unroll
    for (int m = 0; m < 4; ++m)
      #pragma unroll
      for (int n = 0; n < 4; ++n)
        acc[m][n] = __builtin_amdgcn_mfma_f32_16x16x32_bf16(af[m], bfr[n], acc[m][n], 0, 0, 0);
  }
  #pragma unroll
  for (int m = 0; m < 4; ++m)
    #pragma unroll
    for (int n = 0; n < 4; ++n)
      #pragma unroll
      for (int r = 0; r < 4; ++r) {
        int row = bm + wr * 64 + m * 16 + fq * 4 + r;
        int col = bn + wc * 64 + n * 16 + fr;
        C[(size_t)row * N + col] = acc[m][n][r];
      }
}

// ---------- QKV GEMM with fused epilogue: cached_kv + RoPE + bf16 pack ------
// Staging + MFMA core byte-identical to gemm_nt. Epilogue (per round-16-
// verified kv_rope_pack math, operating on the same fp32 values in-register):
//   q-tiles (bn<2048):  RoPE -> bf16 -> qpk[row][col]
//   k-tiles (<4096):    pre-RoPE fp32 -> cached; RoPE -> bf16 -> qpk[row][2048+lc]
//   v-tiles:            pre-RoPE fp32 -> cached+8388608; fp32 -> vbuf (for transpose)
// RoPE pair partner = __shfl_xor(v,1): C-layout col bit0 == lane bit0.
// 128-col tiles never straddle q/k/v boundaries (2048 % 128 == 0).
__global__ __launch_bounds__(256) void gemm_qkv(
    const u16* __restrict__ A, const u16* __restrict__ BT,
    float* __restrict__ cached, u16* __restrict__ qpk,
    float* __restrict__ vbuf, const float2* __restrict__ tab) {
  const int M = ROWS, N = NQKV, K = DIM;
  __shared__ u16 As[128 * 32];
  __shared__ u16 Bs[128 * 32];
  int nbn = N >> 7;                // 48
  int chunk = nbn >> 3;            // 6
  int wg = blockIdx.x;
  int xcd = wg & 7, g = wg >> 3;
  int bm = (g / chunk) * 128;
  int bn = (xcd * chunk + g % chunk) * 128;

  int tid = threadIdx.x;
  int wid = tid >> 6, lane = tid & 63;
  int wr = wid >> 1, wc = wid & 1;
  int fr = lane & 15, fq = lane >> 4;
  int srow_hi = lane >> 2;
  int scol = (lane & 3) * 8;

  f32x4 acc[4][4] = {};

  const u16* a_rd = As + (wr * 64 + fr) * 32 + fq * 8;
  const u16* b_rd = Bs + (wc * 64 + fr) * 32 + fq * 8;

  for (int k0 = 0; k0 < K; k0 += 32) {
    __syncthreads();
    #pragma unroll
    for (int i = 0; i < 2; ++i) {
      int c = wid * 2 + i;
      int row = c * 16 + srow_hi;
      gll16(A  + (size_t)(bm + row) * K + k0 + scol, As + c * 512);
      gll16(BT + (size_t)(bn + row) * K + k0 + scol, Bs + c * 512);
    }
    __syncthreads();

    bf16x8 af[4], bfr[4];
    #pragma unroll
    for (int m = 0; m < 4; ++m) af[m]  = *(const bf16x8*)(a_rd + m * 16 * 32);
    #pragma unroll
    for (int n = 0; n < 4; ++n) bfr[n] = *(const bf16x8*)(b_rd + n * 16 * 32);
    #pragma unroll
    for (int m = 0; m < 4; ++m)
      #pragma unroll
      for (int n = 0; n < 4; ++n)
        acc[m][n] = __builtin_amdgcn_mfma_f32_16x16x32_bf16(af[m], bfr[n], acc[m][n], 0, 0, 0);
  }

  int typ = bn >> 11;              // 0=q, 1=k, 2=v (uniform per block)
  if (typ < 2) {
    #pragma unroll
    for (int m = 0; m < 4; ++m)
      #pragma unroll
      for (int nn = 0; nn < 4; ++nn)
        #pragma unroll
        for (int r = 0; r < 4; ++r) {
          int gr = bm + wr * 64 + m * 16 + fq * 4 + r;
          int gc = bn + wc * 64 + nn * 16 + fr;
          int n = gr & 2047;
          int lc = gc & 2047;
          int d = lc & 127;
          float v = acc[m][nn][r];
          float w = __shfl_xor(v, 1);     // RoPE pair partner (col^1)
          float2 cs = tab[n * 64 + (d >> 1)];
          float o = (d & 1) ? (v * cs.x + w * cs.y) : (v * cs.x - w * cs.y);
          qpk[(size_t)gr * 4096 + typ * 2048 + lc] = f2bf(o);
          if (typ == 1) {
            int b = gr >> 11, h = lc >> 7;
            cached[((size_t)(b * NH + h) * SEQ + n) * DH + d] = v;  // pre-RoPE k
          }
        }
  } else {
    #pragma unroll
    for (int m = 0; m < 4; ++m)
      #pragma unroll
      for (int nn = 0; nn < 4; ++nn)
        #pragma unroll
        for (int r = 0; r < 4; ++r) {
          int gr = bm + wr * 64 + m * 16 + fq * 4 + r;
          int gc = bn + wc * 64 + nn * 16 + fr;
          int n = gr & 2047, b = gr >> 11;
          int lc = gc - 4096;
          int d = lc & 127, h = lc >> 7;
          float v = acc[m][nn][r];
          cached[8388608 + ((size_t)(b * NH + h) * SEQ + n) * DH + d] = v;
          vbuf[(size_t)gr * 2048 + lc] = v;
        }
  }
}

// ------------------------- V transpose + cast -> vT[bh][d][n] (bf16) --------
// [round-6-verified logic; source is now the compact vbuf (row stride 2048)]
__global__ void transpose_v_cast(const float* __restrict__ vbuf,
                                 u16* __restrict__ vT) {
  int bh = blockIdx.z; int b = bh >> 4, h = bh & 15;
  int d0 = blockIdx.x * 32, n0 = blockIdx.y * 32;
  __shared__ float tile[32][33];
  int tx = threadIdx.x, ty = threadIdx.y;   // (32,8)
  const float* src = vbuf + (size_t)(b * SEQ + n0) * 2048 + h * DH + d0;
  #pragma unroll
  for (int j = 0; j < 32; j += 8)
    tile[ty + j][tx] = src[(size_t)(ty + j) * 2048 + tx];
  __syncthreads();
  u16* dst = vT + ((size_t)bh * DH + d0) * SEQ + n0;
  #pragma unroll
  for (int j = 0; j < 32; j += 8)
    dst[(size_t)(ty + j) * SEQ + tx] = f2bf(tile[tx][ty + j]);
}

// -------- swapped-operand 32x32 MFMA causal flash attention, 1 wave ---------
// [VERIFIED round 17 — only the q/k source pointers changed to qpk
//  (row stride 4096 u16; q at +0, k at +2048)]
__global__ __launch_bounds__(64) void attn_swap(
    const u16* __restrict__ qkp,   // packed post-RoPE bf16 q,k: [4096][4096]
    const u16* __restrict__ vT,    // (32,128,2048) bf16
    u16* __restrict__ ctx) {       // (4096, 2048) bf16
  int wg = blockIdx.x;             // 0..1023
  int xcd = wg & 7;
  int g   = wg >> 3;               // 0..127 within-XCD sequence
  int bh  = (g >> 5) * 8 + xcd;    // 0..31 (XCD x owns bh = x,8+x,16+x,24+x)
  int qp  = g & 31;                // pair index
  int b = bh >> 4, h = bh & 15;
  int lane = threadIdx.x;
  int ln = lane & 31;
  int hi = lane >> 5;

  const size_t rstr = 4096;        // u16 per row
  const u16* Qb = qkp + (size_t)(b * SEQ) * rstr + h * 128;
  const u16* Kb = Qb + 2048;
  const u16* Vt = vT + (size_t)bh * DH * SEQ;
  const float scale = 0.08838834764831845f;

  #pragma unroll 1
  for (int ph = 0; ph < 2; ++ph) {
    int qt = ph ? (63 - qp) : qp;  // (qt+1)+(64-qt) = 65 iters per wave
    int qr0 = qt * 32;
    int q_own = qr0 + ln;          // the query this lane's stats cover

    bf16x8 qf[8];
    {
      const u16* qrow = Qb + (size_t)q_own * rstr + hi * 8;
      #pragma unroll
      for (int kc = 0; kc < 8; ++kc) qf[kc] = *(const bf16x8*)(qrow + kc * 16);
    }

    f32x16 acc[4] = {};            // [db] O^T accum: col=d, rows=q
    float m = -3e38f, l = 0.f;

    bf16x8 kreg[8];
    {
      const u16* krow = Kb + (size_t)ln * rstr + hi * 8;
      #pragma unroll
      for (int kc = 0; kc < 8; ++kc) kreg[kc] = *(const bf16x8*)(krow + kc * 16);
    }

    for (int jt = 0; jt <= qt; ++jt) {
      int j0 = jt * 32;

      bf16x8 vfrag[8];             // [t*4+db]: V[j0+t*16+hi*8+e][db*32+ln]
      #pragma unroll
      for (int t = 0; t < 2; ++t)
        #pragma unroll
        for (int db = 0; db < 4; ++db)
          vfrag[t * 4 + db] =
              *(const bf16x8*)(Vt + (size_t)(db * 32 + ln) * SEQ + j0 + t * 16 + hi * 8);

      // QK^T (swapped): S^T[kv][q] — two independent 4-chains, then merge
      f32x16 sacc0 = {}, sacc1 = {};
      __builtin_amdgcn_s_setprio(1);
      #pragma unroll
      for (int kc = 0; kc < 4; ++kc)
        sacc0 = __builtin_amdgcn_mfma_f32_32x32x16_bf16(kreg[kc], qf[kc], sacc0, 0, 0, 0);
      #pragma unroll
      for (int kc = 4; kc < 8; ++kc)
        sacc1 = __builtin_amdgcn_mfma_f32_32x32x16_bf16(kreg[kc], qf[kc], sacc1, 0, 0, 0);
      __builtin_amdgcn_s_setprio(0);
      f32x16 sacc = sacc0 + sacc1;

      // prefetch NEXT K tile (kreg dead after QK issues)
      if (jt < qt) {
        const u16* krow = Kb + (size_t)(j0 + 32 + ln) * rstr + hi * 8;
        #pragma unroll
        for (int kc = 0; kc < 8; ++kc) kreg[kc] = *(const bf16x8*)(krow + kc * 16);
      }

      // mask + scale into lane-local p[16]
      float p[16];
      #pragma unroll
      for (int r = 0; r < 16; ++r) {
        int kv = j0 + (r & 3) + 8 * (r >> 2) + 4 * hi;
        float v = sacc[r] * scale;
        p[r] = (kv > q_own) ? -1e30f : v;
      }

      // lane-local max tree + one cross-half exchange
      float t8[8];
      #pragma unroll
      for (int i = 0; i < 8; ++i) t8[i] = fmaxf(p[i], p[i + 8]);
      #pragma unroll
      for (int i = 0; i < 4; ++i) t8[i] = fmaxf(t8[i], t8[i + 4]);
      float mx = fmaxf(fmaxf(t8[0], t8[1]), fmaxf(t8[2], t8[3]));
      mx = fmaxf(mx, __shfl_xor(mx, 32));

      // T13 defer-max
      if (!__all(mx - m <= 8.f)) {
        float mn = fmaxf(m, mx);
        float al = __expf(m - mn);
        m = mn;
        l *= al;
        #pragma unroll
        for (int r = 0; r < 16; ++r) {
          float alr = __shfl(al, (r & 3) + 8 * (r >> 2) + 4 * hi);
          #pragma unroll
          for (int db = 0; db < 4; ++db) acc[db][r] *= alr;
        }
      }

      // exp + lane-local sum tree + one cross-half exchange
      #pragma unroll
      for (int r = 0; r < 16; ++r) p[r] = __expf(p[r] - m);
      float s8[8];
      #pragma unroll
      for (int i = 0; i < 8; ++i) s8[i] = p[i] + p[i + 8];
      #pragma unroll
      for (int i = 0; i < 4; ++i) s8[i] = s8[i] + s8[i + 4];
      float sum = (s8[0] + s8[1]) + (s8[2] + s8[3]);
      sum += __shfl_xor(sum, 32);
      l += sum;

      // pack P to bf16 pairs, exchange halves, assemble PV A-fragments
      u32 pk[8], swk[8];
      #pragma unroll
      for (int i = 0; i < 8; ++i)
        pk[i] = (u32)f2bf(p[2 * i]) | ((u32)f2bf(p[2 * i + 1]) << 16);
      #pragma unroll
      for (int i = 0; i < 8; ++i) swk[i] = __shfl_xor(pk[i], 32);

      union { u32 w[4]; bf16x8 v; } pf0, pf1;
      pf0.w[0] = hi ? swk[2] : pk[0];
      pf0.w[1] = hi ? swk[3] : pk[1];
      pf0.w[2] = hi ? pk[2]  : swk[0];
      pf0.w[3] = hi ? pk[3]  : swk[1];
      pf1.w[0] = hi ? swk[6] : pk[4];
      pf1.w[1] = hi ? swk[7] : pk[5];
      pf1.w[2] = hi ? pk[6]  : swk[4];
      pf1.w[3] = hi ? pk[7]  : swk[5];

      // PV: O^T[q][d] += P[q][kv] * V[kv][d]
      __builtin_amdgcn_s_setprio(1);
      #pragma unroll
      for (int db = 0; db < 4; ++db) {
        acc[db] = __builtin_amdgcn_mfma_f32_32x32x16_bf16(pf0.v, vfrag[db],     acc[db], 0, 0, 0);
        acc[db] = __builtin_amdgcn_mfma_f32_32x32x16_bf16(pf1.v, vfrag[4 + db], acc[db], 0, 0, 0);
      }
      __builtin_amdgcn_s_setprio(0);
    }

    // epilogue: divide by l (broadcast per output row) and store
    float linv = 1.f / l;
    #pragma unroll
    for (int r = 0; r < 16; ++r) {
      int qrow = (r & 3) + 8 * (r >> 2) + 4 * hi;
      float lr = __shfl(linv, qrow);
      int q = qr0 + qrow;
      u16* crow = ctx + (size_t)(b * SEQ + q) * DIM + h * DH + ln;
      #pragma unroll
      for (int db = 0; db < 4; ++db)
        crow[db * 32] = f2bf(acc[db][r] * lr);
    }
  }
}

// ----------------------------------------------------------------- launch ---
extern "C" void kernel_launch(void* const* d_in, const int* in_sizes, int n_in,
                              void* d_out, int out_size, void* d_ws, size_t ws_size,
                              hipStream_t stream) {
  // size-keyed input selection (sizes are pairwise distinct)
  const float *x = nullptr, *gamma = nullptr, *wq = nullptr, *wo = nullptr;
  for (int ii = 0; ii < n_in; ++ii) {
    switch (in_sizes[ii]) {
      case  8388608: x     = (const float*)d_in[ii]; break;
      case     2048: gamma = (const float*)d_in[ii]; break;
      case 12582912: wq    = (const float*)d_in[ii]; break;
      case  4194304: wo    = (const float*)d_in[ii]; break;
    }
  }
  if (!x || !gamma || !wq || !wo) {   // fallback: documented dict order
    x = (const float*)d_in[0]; gamma = (const float*)d_in[1];
    wq = (const float*)d_in[2]; wo = (const float*)d_in[3];
  }

  float* out    = (float*)d_out;           // (2,2048,2048) = first 33.55 MB
  float* cached = out + 8388608;           // (2,2,16,2048,128) at byte 33.55M

  // ws layout (exactly 128 MiB, the proven envelope):
  //   [0,       16.78M)  xnb   (bf16 A for QKV GEMM)
  //   [16.78M,  50.33M)  qpk   (packed post-RoPE bf16 q,k: [4096][4096])
  //   [50.33M,  83.89M)  vbuf  (fp32 v: [4096][2048])
  //   [83.89M, 109.05M)  wqkvT (bf16)
  //   [109.05M,117.44M)  woutT (bf16)
  //   [117.44M,134.22M)  ctx   (bf16)
  // out-region scratch (dead before final GEMM writes out):
  //   out[0, 16.78M)     vT (bf16)
  //   out[16.78M,17.83M) rope table
  char* ws = (char*)d_ws;
  u16*   xnb   = (u16*)ws;
  u16*   qpk   = (u16*)(ws + 16777216);
  float* vbuf  = (float*)(ws + 50331648);
  u16*   wqkvT = (u16*)(ws + 83886080);
  u16*   woutT = (u16*)(ws + 109051904);
  u16*   ctx   = (u16*)(ws + 117440512);
  u16*   vT    = (u16*)d_out;
  float2* tab  = (float2*)((char*)d_out + 16777216);

  rms_bf16<<<ROWS, 64, 0, stream>>>(x, gamma, xnb);
  rope_table<<<131072 / 256, 256, 0, stream>>>(tab);
  transpose_f32_bf16<<<dim3(NQKV / 32, DIM / 32), dim3(32, 8), 0, stream>>>(wq, wqkvT, DIM, NQKV);
  transpose_f32_bf16<<<dim3(DIM / 32, DIM / 32), dim3(32, 8), 0, stream>>>(wo, woutT, DIM, DIM);
  gemm_qkv<<<(ROWS / 128) * (NQKV / 128), 256, 0, stream>>>(xnb, wqkvT, cached, qpk, vbuf, tab);
  transpose_v_cast<<<dim3(DH / 32, SEQ / 32, 32), dim3(32, 8), 0, stream>>>(vbuf, vT);
  attn_swap<<<1024, 64, 0, stream>>>(qpk, vT, ctx);
  gemm_nt<<<(ROWS / 128) * (DIM / 128), 256, 0, stream>>>(ctx, woutT, out, ROWS, DIM, DIM);
}